// Round 16
// baseline (830.214 us; speedup 1.0000x reference)
//
#include <hip/hip_runtime.h>

#define NN 100000
#define NCELL 40000
#define NDRUG 60000
#define EE 1600000
#define FEPS 1e-5f
#define SLOPE 0.2f
#define NB 391    // dst-buckets (256 rows each)
#define SCH 8192  // edges per sort block
#define SNB 196   // ceil(EE/SCH)

typedef unsigned short ushort_t;
typedef unsigned int uint_t;
typedef __attribute__((ext_vector_type(8))) __bf16 bf16x8;
typedef __attribute__((ext_vector_type(4))) float f32x4;
typedef __attribute__((ext_vector_type(2))) float f32x2;

__device__ __forceinline__ ushort_t f2bf(float x) {
  uint_t u = __float_as_uint(x);
  u = (u + 0x7FFFu + ((u >> 16) & 1u)) >> 16;  // RNE
  return (ushort_t)u;
}
__device__ __forceinline__ uint_t pack2bf(float a, float b) {
  return (uint_t)f2bf(a) | ((uint_t)f2bf(b) << 16);
}
__device__ __forceinline__ float bf2f(ushort_t x) {
  return __uint_as_float(((uint_t)x) << 16);
}
__device__ __forceinline__ f32x2 u2f2(uint_t u) {
  f32x2 r;
  r.x = __uint_as_float(u << 16);
  r.y = __uint_as_float(u & 0xFFFF0000u);
  return r;
}

// ---------------------------------------------------------------- converts
__global__ __launch_bounds__(256) void feat_cvt_k(const float* __restrict__ X,
                                                  ushort_t* __restrict__ Y, int n8) {
  int i = blockIdx.x * 256 + threadIdx.x;
  if (i >= n8) return;
  const float4* in4 = (const float4*)X;
  float4 a = in4[2 * i], b = in4[2 * i + 1];
  uint4 o;
  o.x = pack2bf(a.x, a.y); o.y = pack2bf(a.z, a.w);
  o.z = pack2bf(b.x, b.y); o.w = pack2bf(b.z, b.w);
  ((uint4*)Y)[i] = o;
}

struct WC { const float* s; ushort_t* d; int K; };
struct WCA { WC w[6]; };
__global__ __launch_bounds__(128) void wcvt_k(WCA a) {
  const WC wc = a.w[blockIdx.x];
  const int k0 = blockIdx.y * 16;
  if (k0 >= wc.K) return;
  const int col = threadIdx.x;
  const int k1 = min(k0 + 16, wc.K);
  for (int k = k0; k < k1; k++)
    wc.d[(size_t)col * wc.K + k] = f2bf(wc.s[(size_t)k * 128 + col]);
}

// ---- CSR build: deterministic bucket partition, zero global atomics ----
__global__ __launch_bounds__(256) void sort_count_k(const int* __restrict__ dst,
                                                    int* __restrict__ tbl, int E) {
  __shared__ int cnt[NB];
  const int blk = blockIdx.x;
  for (int i = threadIdx.x; i < NB; i += 256) cnt[i] = 0;
  __syncthreads();
  const int e0 = blk * SCH, e1 = min(e0 + SCH, E);
  for (int e = e0 + threadIdx.x; e < e1; e += 256) atomicAdd(&cnt[dst[e] >> 8], 1);
  __syncthreads();
  for (int i = threadIdx.x; i < NB; i += 256) tbl[i * SNB + blk] = cnt[i];
}

__global__ __launch_bounds__(256) void bkt_total_k(const int* __restrict__ tbl,
                                                   int* __restrict__ total) {
  __shared__ int sm[256];
  const int b = blockIdx.x;
  const int t = threadIdx.x;
  sm[t] = (t < SNB) ? tbl[b * SNB + t] : 0;
  __syncthreads();
  for (int off = 128; off > 0; off >>= 1) {
    if (t < off) sm[t] += sm[t + off];
    __syncthreads();
  }
  if (t == 0) total[b] = sm[0];
}

__global__ __launch_bounds__(512) void bkt_scan_k(const int* __restrict__ total,
                                                  int* __restrict__ bktoff,
                                                  int* __restrict__ rowp, int n, int E) {
  __shared__ int sm[512];
  const int t = threadIdx.x;
  const int v = (t < NB) ? total[t] : 0;
  sm[t] = v;
  __syncthreads();
  for (int off = 1; off < 512; off <<= 1) {
    int u = (t >= off) ? sm[t - off] : 0;
    __syncthreads();
    sm[t] += u;
    __syncthreads();
  }
  if (t < NB) bktoff[t] = sm[t] - v;
  if (t == 0) { bktoff[NB] = E; rowp[n] = E; }
}

__global__ __launch_bounds__(256) void sort_offset_k(const int* __restrict__ tbl,
                                                     const int* __restrict__ bktoff,
                                                     int* __restrict__ off) {
  __shared__ int sm[256];
  const int b = blockIdx.x;
  const int t = threadIdx.x;
  const int v = (t < SNB) ? tbl[b * SNB + t] : 0;
  sm[t] = v;
  __syncthreads();
  for (int o = 1; o < 256; o <<= 1) {
    int u = (t >= o) ? sm[t - o] : 0;
    __syncthreads();
    sm[t] += u;
    __syncthreads();
  }
  if (t < SNB) off[b * SNB + t] = bktoff[b] + sm[t] - v;
}

__global__ __launch_bounds__(256) void sort_place_k(const int* __restrict__ src,
                                                    const int* __restrict__ dst,
                                                    const int* __restrict__ off,
                                                    uint_t* __restrict__ ebuf, int E) {
  __shared__ int pos[NB];
  const int blk = blockIdx.x;
  for (int i = threadIdx.x; i < NB; i += 256) pos[i] = off[i * SNB + blk];
  __syncthreads();
  const int e0 = blk * SCH, e1 = min(e0 + SCH, E);
  for (int e = e0 + threadIdx.x; e < e1; e += 256) {
    const int d = dst[e];
    const int p = atomicAdd(&pos[d >> 8], 1);
    ebuf[p] = (uint_t)src[e] | ((uint_t)(d & 255) << 17);
  }
}

__global__ __launch_bounds__(256) void bucket_fill2_k(const uint_t* __restrict__ ebuf,
                                                      const int* __restrict__ bktoff,
                                                      int* __restrict__ rowp,
                                                      float* __restrict__ dis,
                                                      int* __restrict__ esrc, int n) {
  __shared__ int hist[256];
  __shared__ int scn[256];
  const int b = blockIdx.x;
  const int t = threadIdx.x;
  const int r0 = b << 8;
  const int base = bktoff[b];
  const int end = bktoff[b + 1];
  hist[t] = 0;
  __syncthreads();
  for (int i = base + t; i < end; i += 256)
    atomicAdd(&hist[ebuf[i] >> 17], 1);
  __syncthreads();
  const int d = hist[t];
  scn[t] = d;
  __syncthreads();
  for (int off = 1; off < 256; off <<= 1) {
    int u = (t >= off) ? scn[t - off] : 0;
    __syncthreads();
    scn[t] += u;
    __syncthreads();
  }
  const int excl = scn[t] - d;
  const int r = r0 + t;
  if (r < n) {
    rowp[r] = base + excl;
    dis[r] = (d > 0) ? rsqrtf((float)d) : 0.f;
  }
  __syncthreads();
  hist[t] = excl;  // reuse as cursors
  __syncthreads();
  for (int i = base + t; i < end; i += 256) {
    const uint_t v = ebuf[i];
    const int rl = (int)(v >> 17);
    const int p = atomicAdd(&hist[rl], 1);
    esrc[base + p] = (int)(v & 0x1FFFFu);
  }
}

// augment: per-edge (byte offset, dis[src]) pairs
__global__ __launch_bounds__(256) void esrc_aug_k(const int* __restrict__ esrc,
                                                  const float* __restrict__ dis,
                                                  int2* __restrict__ esrc2, int E) {
  int i = blockIdx.x * 256 + threadIdx.x;
  if (i >= E) return;
  const int s = esrc[i];
  esrc2[i] = make_int2(s * 256, __float_as_int(dis[s]));
}

// ---------------------------------------------------------------- MFMA GEMM
// B-only LDS (32KB, SWZ-swizzled 256B rows); A read direct from global (each
// row consumed by exactly one wave; 4-lgrp 16B reads cover full 64B lines).
// B regs reload for seg+1 right after store -> reg-level double buffer.
// LDS 33KB -> 4 blocks/CU. Epilogue: fp32 bounce in two 64-row passes [64][129].
#define SWZ(base, row, byte) ((char*)(base) + (((row)*256 + (byte)) ^ (((row)&7) << 4)))
#define FPAD 129
__global__ __launch_bounds__(256) void gemm_mfma_k(const ushort_t* __restrict__ X0,
                                                   const ushort_t* __restrict__ X1,
                                                   const ushort_t* __restrict__ X2,
                                                   const ushort_t* __restrict__ Wt,
                                                   const float* __restrict__ bias,
                                                   float* __restrict__ Yf,
                                                   ushort_t* __restrict__ Yb,
                                                   int nrows, int nseg, int act) {
  __shared__ float smemf[64 * FPAD];        // 33024 B; B staging uses first 32768
  ushort_t* sB = (ushort_t*)smemf;
  const int t = threadIdx.x;
  const int wave = t >> 6;
  const int lane = t & 63;
  const int lane15 = lane & 15;
  const int lgrp = lane >> 4;  // 0..3
  const int row0 = blockIdx.x * 128;
  const int Ktot = nseg * 128;

  const int tr = t >> 1;        // staged B col / epilogue row
  const int th = (t & 1) * 64;  // half offset (elems)
  const int wb = th * 2;        // byte offset

  const int rA0 = min(row0 + wave * 32 + lane15, nrows - 1);
  const int rA1 = min(row0 + wave * 32 + 16 + lane15, nrows - 1);

  f32x4 acc[2][8];
#pragma unroll
  for (int m = 0; m < 2; m++)
#pragma unroll
    for (int f = 0; f < 8; f++) acc[m][f] = (f32x4)0.f;

  const ushort_t* Bp = Wt + (size_t)tr * Ktot + th;
  uint4 b0 = *(const uint4*)(Bp + 0);
  uint4 b1 = *(const uint4*)(Bp + 8);
  uint4 b2 = *(const uint4*)(Bp + 16);
  uint4 b3 = *(const uint4*)(Bp + 24);
  uint4 b4 = *(const uint4*)(Bp + 32);
  uint4 b5 = *(const uint4*)(Bp + 40);
  uint4 b6 = *(const uint4*)(Bp + 48);
  uint4 b7 = *(const uint4*)(Bp + 56);

  for (int seg = 0; seg < nseg; seg++) {
    if (seg) __syncthreads();  // all waves done computing previous sB
    *(uint4*)SWZ(sB, tr, wb + 0) = b0;
    *(uint4*)SWZ(sB, tr, wb + 16) = b1;
    *(uint4*)SWZ(sB, tr, wb + 32) = b2;
    *(uint4*)SWZ(sB, tr, wb + 48) = b3;
    *(uint4*)SWZ(sB, tr, wb + 64) = b4;
    *(uint4*)SWZ(sB, tr, wb + 80) = b5;
    *(uint4*)SWZ(sB, tr, wb + 96) = b6;
    *(uint4*)SWZ(sB, tr, wb + 112) = b7;
    __syncthreads();
    if (seg + 1 < nseg) {  // reg double-buffer: issue next B loads, overlap compute
      const ushort_t* Bn = Bp + ((seg + 1) << 7);
      b0 = *(const uint4*)(Bn + 0);
      b1 = *(const uint4*)(Bn + 8);
      b2 = *(const uint4*)(Bn + 16);
      b3 = *(const uint4*)(Bn + 24);
      b4 = *(const uint4*)(Bn + 32);
      b5 = *(const uint4*)(Bn + 40);
      b6 = *(const uint4*)(Bn + 48);
      b7 = *(const uint4*)(Bn + 56);
    }
    const ushort_t* XA = (seg == 0) ? X0 : ((seg == 1) ? X1 : X2);
    const ushort_t* A0 = XA + (size_t)rA0 * 128;
    const ushort_t* A1 = XA + (size_t)rA1 * 128;
    const bf16x8 av00 = *(const bf16x8*)(A0 + lgrp * 8);
    const bf16x8 av01 = *(const bf16x8*)(A1 + lgrp * 8);
    const bf16x8 av10 = *(const bf16x8*)(A0 + 32 + lgrp * 8);
    const bf16x8 av11 = *(const bf16x8*)(A1 + 32 + lgrp * 8);
    const bf16x8 av20 = *(const bf16x8*)(A0 + 64 + lgrp * 8);
    const bf16x8 av21 = *(const bf16x8*)(A1 + 64 + lgrp * 8);
    const bf16x8 av30 = *(const bf16x8*)(A0 + 96 + lgrp * 8);
    const bf16x8 av31 = *(const bf16x8*)(A1 + 96 + lgrp * 8);
#pragma unroll
    for (int kk = 0; kk < 4; kk++) {
      const bf16x8 a0v = (kk == 0) ? av00 : (kk == 1) ? av10 : (kk == 2) ? av20 : av30;
      const bf16x8 a1v = (kk == 0) ? av01 : (kk == 1) ? av11 : (kk == 2) ? av21 : av31;
      const int cb = kk * 64 + lgrp * 16;
#pragma unroll
      for (int f = 0; f < 8; f++) {
        bf16x8 wv = *(const bf16x8*)SWZ(sB, f * 16 + lane15, cb);
        acc[0][f] = __builtin_amdgcn_mfma_f32_16x16x32_bf16(a0v, wv, acc[0][f], 0, 0, 0);
        acc[1][f] = __builtin_amdgcn_mfma_f32_16x16x32_bf16(a1v, wv, acc[1][f], 0, 0, 0);
      }
    }
  }

  // ---- epilogue: two 64-row passes through smemf [64][FPAD] ----
  const int rowg = row0 + tr;
  const int lr = tr & 63;
#pragma unroll
  for (int pass = 0; pass < 2; pass++) {
    __syncthreads();
    if ((wave >> 1) == pass) {
      const int rl = (wave & 1) * 32;
#pragma unroll
      for (int m = 0; m < 2; m++)
#pragma unroll
        for (int f = 0; f < 8; f++)
#pragma unroll
          for (int j = 0; j < 4; j++)
            smemf[(rl + m * 16 + lgrp * 4 + j) * FPAD + f * 16 + lane15] = acc[m][f][j];
    }
    __syncthreads();
    if ((tr >> 6) == pass && rowg < nrows) {
      const float* rp = smemf + lr * FPAD + th;
      if (Yf) {
        float* yp = Yf + (size_t)rowg * 128 + th;
#pragma unroll
        for (int q = 0; q < 16; q++) {
          float4 v = ((const float4*)rp)[q];
          if (bias) {
            const float4 bv = ((const float4*)(bias + th))[q];
            v.x += bv.x; v.y += bv.y; v.z += bv.z; v.w += bv.w;
          }
          if (act == 1) {
            v.x = v.x > 0.f ? v.x : SLOPE * v.x; v.y = v.y > 0.f ? v.y : SLOPE * v.y;
            v.z = v.z > 0.f ? v.z : SLOPE * v.z; v.w = v.w > 0.f ? v.w : SLOPE * v.w;
          } else if (act == 2) {
            v.x = v.x > 0.f ? v.x : 0.f; v.y = v.y > 0.f ? v.y : 0.f;
            v.z = v.z > 0.f ? v.z : 0.f; v.w = v.w > 0.f ? v.w : 0.f;
          }
          ((float4*)yp)[q] = v;
        }
      } else {
        ushort_t* yp = Yb + (size_t)rowg * 128 + th;
#pragma unroll
        for (int q = 0; q < 8; q++) {
          float4 v0 = ((const float4*)rp)[2 * q];
          float4 v1 = ((const float4*)rp)[2 * q + 1];
          if (bias) {
            const float4 c0 = ((const float4*)(bias + th))[2 * q];
            const float4 c1 = ((const float4*)(bias + th))[2 * q + 1];
            v0.x += c0.x; v0.y += c0.y; v0.z += c0.z; v0.w += c0.w;
            v1.x += c1.x; v1.y += c1.y; v1.z += c1.z; v1.w += c1.w;
          }
          if (act == 1) {
            v0.x = v0.x > 0.f ? v0.x : SLOPE * v0.x; v0.y = v0.y > 0.f ? v0.y : SLOPE * v0.y;
            v0.z = v0.z > 0.f ? v0.z : SLOPE * v0.z; v0.w = v0.w > 0.f ? v0.w : SLOPE * v0.w;
            v1.x = v1.x > 0.f ? v1.x : SLOPE * v1.x; v1.y = v1.y > 0.f ? v1.y : SLOPE * v1.y;
            v1.z = v1.z > 0.f ? v1.z : SLOPE * v1.z; v1.w = v1.w > 0.f ? v1.w : SLOPE * v1.w;
          } else if (act == 2) {
            v0.x = v0.x > 0.f ? v0.x : 0.f; v0.y = v0.y > 0.f ? v0.y : 0.f;
            v0.z = v0.z > 0.f ? v0.z : 0.f; v0.w = v0.w > 0.f ? v0.w : 0.f;
            v1.x = v1.x > 0.f ? v1.x : 0.f; v1.y = v1.y > 0.f ? v1.y : 0.f;
            v1.z = v1.z > 0.f ? v1.z : 0.f; v1.w = v1.w > 0.f ? v1.w : 0.f;
          }
          uint4 o;
          o.x = pack2bf(v0.x, v0.y); o.y = pack2bf(v0.z, v0.w);
          o.z = pack2bf(v1.x, v1.y); o.w = pack2bf(v1.z, v1.w);
          ((uint4*)yp)[q] = o;
        }
      }
    }
  }
}

// ---------------------------------------------------------------- gather (bf16)
__global__ __launch_bounds__(256) void gcn_gather_k(const ushort_t* __restrict__ xw,
                                                    const int* __restrict__ rowp,
                                                    const int2* __restrict__ esrc2,
                                                    const float* __restrict__ dis,
                                                    const float* __restrict__ bias,
                                                    ushort_t* __restrict__ out, int nrows) {
  const int lane = threadIdx.x & 63;
  const int row = (blockIdx.x * blockDim.x + threadIdx.x) >> 6;
  if (row >= nrows) return;
  const int slot = lane >> 4;
  const int ch = lane & 15;
  const int start = rowp[row];
  const int end = rowp[row + 1];
  const float dr = dis[row];
  const char* xwb_ = (const char*)xw;
  const int chb = ch * 16;

  f32x2 a01 = {0.f, 0.f}, a23 = {0.f, 0.f}, a45 = {0.f, 0.f}, a67 = {0.f, 0.f};
  for (int j = start + slot; j < end; j += 8) {
    const int2 e1 = esrc2[j];
    const int j2 = j + 4;
    const bool h2 = j2 < end;
    const int2 e2 = h2 ? esrc2[j2] : e1;
    const float w1 = __int_as_float(e1.y);
    const float w2 = h2 ? __int_as_float(e2.y) : 0.f;
    const uint4 v1 = *(const uint4*)(xwb_ + (size_t)(uint_t)e1.x + chb);
    const uint4 v2 = *(const uint4*)(xwb_ + (size_t)(uint_t)e2.x + chb);
    f32x2 wp1; wp1.x = w1; wp1.y = w1;
    f32x2 wp2; wp2.x = w2; wp2.y = w2;
    a01 += wp1 * u2f2(v1.x) + wp2 * u2f2(v2.x);
    a23 += wp1 * u2f2(v1.y) + wp2 * u2f2(v2.y);
    a45 += wp1 * u2f2(v1.z) + wp2 * u2f2(v2.z);
    a67 += wp1 * u2f2(v1.w) + wp2 * u2f2(v2.w);
  }
  float a0 = a01.x, a1 = a01.y, a2 = a23.x, a3 = a23.y;
  float a4 = a45.x, a5 = a45.y, a6 = a67.x, a7 = a67.y;
  a0 += __shfl_xor(a0, 16, 64); a1 += __shfl_xor(a1, 16, 64);
  a2 += __shfl_xor(a2, 16, 64); a3 += __shfl_xor(a3, 16, 64);
  a4 += __shfl_xor(a4, 16, 64); a5 += __shfl_xor(a5, 16, 64);
  a6 += __shfl_xor(a6, 16, 64); a7 += __shfl_xor(a7, 16, 64);
  a0 += __shfl_xor(a0, 32, 64); a1 += __shfl_xor(a1, 32, 64);
  a2 += __shfl_xor(a2, 32, 64); a3 += __shfl_xor(a3, 32, 64);
  a4 += __shfl_xor(a4, 32, 64); a5 += __shfl_xor(a5, 32, 64);
  a6 += __shfl_xor(a6, 32, 64); a7 += __shfl_xor(a7, 32, 64);

  if (slot == 0) {
    const float4 b0 = *(const float4*)(bias + ch * 8);
    const float4 b1 = *(const float4*)(bias + ch * 8 + 4);
    float o0 = dr * a0 + b0.x, o1 = dr * a1 + b0.y;
    float o2 = dr * a2 + b0.z, o3 = dr * a3 + b0.w;
    float o4 = dr * a4 + b1.x, o5 = dr * a5 + b1.y;
    float o6 = dr * a6 + b1.z, o7 = dr * a7 + b1.w;
    o0 = o0 > 0.f ? o0 : SLOPE * o0; o1 = o1 > 0.f ? o1 : SLOPE * o1;
    o2 = o2 > 0.f ? o2 : SLOPE * o2; o3 = o3 > 0.f ? o3 : SLOPE * o3;
    o4 = o4 > 0.f ? o4 : SLOPE * o4; o5 = o5 > 0.f ? o5 : SLOPE * o5;
    o6 = o6 > 0.f ? o6 : SLOPE * o6; o7 = o7 > 0.f ? o7 : SLOPE * o7;
    uint4 o;
    o.x = pack2bf(o0, o1); o.y = pack2bf(o2, o3);
    o.z = pack2bf(o4, o5); o.w = pack2bf(o6, o7);
    *(uint4*)(out + (size_t)row * 128 + ch * 8) = o;
  }
}

// ---------------------------------------------------------------- batchnorm
__global__ __launch_bounds__(256) void bn_stats_k(const ushort_t* __restrict__ X,
                                                  float* __restrict__ sums,
                                                  float* __restrict__ sumsq, int nrows) {
  __shared__ float ls[256], lq[256];
  const int t = threadIdx.x;
  const int c = t & 127;
  const int h = t >> 7;
  const int r0 = blockIdx.x * 256;
  const int r1 = min(r0 + 256, nrows);
  float s = 0.f, q = 0.f;
  for (int r = r0 + h; r < r1; r += 2) {
    float v = bf2f(X[(size_t)r * 128 + c]);
    s += v;
    q += v * v;
  }
  ls[t] = s;
  lq[t] = q;
  __syncthreads();
  if (t < 128) {
    s = ls[t] + ls[t + 128];
    q = lq[t] + lq[t + 128];
    atomicAdd(&sums[c], s);
    atomicAdd(&sumsq[c], q);
  }
}

__global__ void bn_finalize_k(const float* __restrict__ sums,
                              const float* __restrict__ sumsq,
                              const float* __restrict__ g,
                              const float* __restrict__ be,
                              float* __restrict__ scl, float* __restrict__ sht) {
  int c = threadIdx.x;
  float mu = sums[c] * (1.f / (float)NN);
  float var = sumsq[c] * (1.f / (float)NN) - mu * mu;
  float s = g[c] * rsqrtf(var + FEPS);
  scl[c] = s;
  sht[c] = be[c] - mu * s;
}

// fold BN affine into head weight
__global__ __launch_bounds__(128) void fold_head_k(const float* __restrict__ W,
                                                   const float* __restrict__ b,
                                                   const float* __restrict__ sclS,
                                                   const float* __restrict__ shtS,
                                                   const float* __restrict__ sclR,
                                                   const float* __restrict__ shtR,
                                                   ushort_t* __restrict__ Wf,
                                                   float* __restrict__ bf) {
  const int col = threadIdx.x;
  float acc = b[col];
  for (int k = 0; k < 256; k++) {
    const float w = W[(size_t)k * 128 + col];
    const float sc = (k < 128) ? sclS[k] : sclR[k - 128];
    const float sh = (k < 128) ? shtS[k] : shtR[k - 128];
    acc += sh * w;
    Wf[(size_t)col * 256 + k] = f2bf(sc * w);
  }
  bf[col] = acc;
}

// ---------------------------------------------------------------- launch
extern "C" void kernel_launch(void* const* d_in, const int* in_sizes, int n_in,
                              void* d_out, int out_size, void* d_ws, size_t ws_size,
                              hipStream_t stream) {
  const float* feature = (const float*)d_in[0];
  const int* sen_edge = (const int*)d_in[1];
  const int* res_edge = (const int*)d_in[2];
  const float* W_sen1 = (const float*)d_in[3];
  const float* b_sen1 = (const float*)d_in[4];
  const float* W_sen2 = (const float*)d_in[5];
  const float* b_sen2 = (const float*)d_in[6];
  const float* W_senfc = (const float*)d_in[7];
  const float* b_senfc = (const float*)d_in[8];
  const float* g_sen = (const float*)d_in[9];
  const float* be_sen = (const float*)d_in[10];
  const float* W_res1 = (const float*)d_in[11];
  const float* b_res1 = (const float*)d_in[12];
  const float* W_res2 = (const float*)d_in[13];
  const float* b_res2 = (const float*)d_in[14];
  const float* W_resfc = (const float*)d_in[15];
  const float* b_resfc = (const float*)d_in[16];
  const float* g_res = (const float*)d_in[17];
  const float* be_res = (const float*)d_in[18];
  const float* W_cell = (const float*)d_in[19];
  const float* b_cell = (const float*)d_in[20];
  const float* W_drug = (const float*)d_in[21];
  const float* b_drug = (const float*)d_in[22];
  float* out = (float*)d_out;

  const size_t NF = (size_t)NN * 128;
  char* wsb = (char*)d_ws;
  ushort_t* featb = (ushort_t*)wsb;                 // NF bf16 each
  ushort_t* x1b = featb + NF;
  ushort_t* x2b = x1b + NF;
  ushort_t* xwb = x2b + NF;
  ushort_t* xallSb = xwb + NF;
  ushort_t* xallRb = xallSb + NF;
  ushort_t* wt = xallRb + NF;                       // weight pool
  ushort_t* W1tS = wt;                              // 128*128
  ushort_t* W2tS = W1tS + 128 * 128;
  ushort_t* WfctS = W2tS + 128 * 128;               // 128*384
  ushort_t* W1tR = WfctS + 128 * 384;
  ushort_t* W2tR = W1tR + 128 * 128;
  ushort_t* WfctR = W2tR + 128 * 128;
  ushort_t* Wcellf = WfctR + 128 * 384;             // 128*256 (folded)
  ushort_t* Wdrugf = Wcellf + 128 * 256;
  float* dis = (float*)(Wdrugf + 128 * 256);        // NN
  int* rowp = (int*)(dis + NN);                     // NN+1
  int* esrc = rowp + (NN + 1);                      // EE
  int2* esrc2 = (int2*)(esrc + EE);                 // EE int2
  uint_t* ebuf = (uint_t*)(esrc2 + EE);             // EE
  int* tbl = (int*)(ebuf + EE);                     // NB*SNB
  int* off = tbl + NB * SNB;                        // NB*SNB
  int* total = off + NB * SNB;                      // NB
  int* bktoff = total + NB;                         // NB+1
  float* sums = (float*)(bktoff + NB + 1);          // 128
  float* sumsq = sums + 128;
  float* sclS = sumsq + 128;
  float* shtS = sclS + 128;
  float* sclR = shtS + 128;
  float* shtR = sclR + 128;
  float* bcellf = shtR + 128;
  float* bdrugf = bcellf + 128;

  const int MG = (NN + 127) / 128;          // 782
  const int GATH_N = (NN * 64 + 255) / 256; // 25000
  const int EB = (EE + 255) / 256;          // 6250
  const int STAT_N = (NN + 255) / 256;      // 391

  feat_cvt_k<<<(int)(NF / 8 + 255) / 256, 256, 0, stream>>>(feature, featb, (int)(NF / 8));
  WCA wa;
  wa.w[0] = {W_sen1, W1tS, 128};  wa.w[1] = {W_sen2, W2tS, 128};
  wa.w[2] = {W_senfc, WfctS, 384}; wa.w[3] = {W_res1, W1tR, 128};
  wa.w[4] = {W_res2, W2tR, 128};  wa.w[5] = {W_resfc, WfctR, 384};
  wcvt_k<<<dim3(6, 24), 128, 0, stream>>>(wa);

  struct Branch {
    const int* edge;
    ushort_t* W1t; const float* b1;
    ushort_t* W2t; const float* b2;
    ushort_t* Wfct; const float* bfc;
    const float* g; const float* be;
    ushort_t* xallb; float* scl; float* sht;
  };
  Branch br[2] = {
      {sen_edge, W1tS, b_sen1, W2tS, b_sen2, WfctS, b_senfc, g_sen, be_sen, xallSb, sclS, shtS},
      {res_edge, W1tR, b_res1, W2tR, b_res2, WfctR, b_resfc, g_res, be_res, xallRb, sclR, shtR},
  };

  for (int b = 0; b < 2; b++) {
    const int* src = br[b].edge;
    const int* dst = br[b].edge + EE;
    // CSR build: no global atomics anywhere
    sort_count_k<<<SNB, 256, 0, stream>>>(dst, tbl, EE);
    bkt_total_k<<<NB, 256, 0, stream>>>(tbl, total);
    bkt_scan_k<<<1, 512, 0, stream>>>(total, bktoff, rowp, NN, EE);
    sort_offset_k<<<NB, 256, 0, stream>>>(tbl, bktoff, off);
    sort_place_k<<<SNB, 256, 0, stream>>>(src, dst, off, ebuf, EE);
    bucket_fill2_k<<<NB, 256, 0, stream>>>(ebuf, bktoff, rowp, dis, esrc, NN);
    esrc_aug_k<<<EB, 256, 0, stream>>>(esrc, dis, esrc2, EE);
    // layer 1
    gemm_mfma_k<<<MG, 256, 0, stream>>>(featb, nullptr, nullptr, br[b].W1t, nullptr,
                                        nullptr, xwb, NN, 1, 0);
    gcn_gather_k<<<GATH_N, 256, 0, stream>>>(xwb, rowp, esrc2, dis, br[b].b1, x1b, NN);
    // layer 2
    gemm_mfma_k<<<MG, 256, 0, stream>>>(x1b, nullptr, nullptr, br[b].W2t, nullptr,
                                        nullptr, xwb, NN, 1, 0);
    gcn_gather_k<<<GATH_N, 256, 0, stream>>>(xwb, rowp, esrc2, dis, br[b].b2, x2b, NN);
    // fc
    gemm_mfma_k<<<MG, 256, 0, stream>>>(featb, x1b, x2b, br[b].Wfct, br[b].bfc,
                                        nullptr, br[b].xallb, NN, 3, 2);
    // batchnorm stats
    (void)hipMemsetAsync(sums, 0, 2 * 128 * sizeof(float), stream);
    bn_stats_k<<<STAT_N, 256, 0, stream>>>(br[b].xallb, sums, sumsq, NN);
    bn_finalize_k<<<1, 128, 0, stream>>>(sums, sumsq, br[b].g, br[b].be, br[b].scl, br[b].sht);
  }

  fold_head_k<<<1, 128, 0, stream>>>(W_cell, b_cell, sclS, shtS, sclR, shtR, Wcellf, bcellf);
  fold_head_k<<<1, 128, 0, stream>>>(W_drug, b_drug, sclS, shtS, sclR, shtR, Wdrugf, bdrugf);
  const int MGC = (NCELL + 127) / 128;
  const int MGD = (NDRUG + 127) / 128;
  gemm_mfma_k<<<MGC, 256, 0, stream>>>(xallSb, xallRb, nullptr, Wcellf, bcellf,
                                       out, nullptr, NCELL, 2, 2);
  float* outD = out + (size_t)NCELL * 128;
  gemm_mfma_k<<<MGD, 256, 0, stream>>>(xallSb + (size_t)NCELL * 128, xallRb + (size_t)NCELL * 128,
                                       nullptr, Wdrugf, bdrugf, outD, nullptr, NDRUG, 2, 2);
}

// Round 18
// 726.439 us; speedup vs baseline: 1.1429x; 1.1429x over previous
//
#include <hip/hip_runtime.h>

#define NN 100000
#define NCELL 40000
#define NDRUG 60000
#define EE 1600000
#define FEPS 1e-5f
#define SLOPE 0.2f
#define NB 391    // dst-buckets (256 rows each)
#define SCH 8192  // edges per sort block
#define SNB 196   // ceil(EE/SCH)

typedef unsigned short ushort_t;
typedef unsigned int uint_t;
typedef __attribute__((ext_vector_type(8))) __bf16 bf16x8;
typedef __attribute__((ext_vector_type(4))) float f32x4;
typedef __attribute__((ext_vector_type(2))) float f32x2;

__device__ __forceinline__ ushort_t f2bf(float x) {
  uint_t u = __float_as_uint(x);
  u = (u + 0x7FFFu + ((u >> 16) & 1u)) >> 16;  // RNE
  return (ushort_t)u;
}
__device__ __forceinline__ uint_t pack2bf(float a, float b) {
  return (uint_t)f2bf(a) | ((uint_t)f2bf(b) << 16);
}
__device__ __forceinline__ float bf2f(ushort_t x) {
  return __uint_as_float(((uint_t)x) << 16);
}

// ---------------------------------------------------------------- converts
__global__ __launch_bounds__(256) void feat_cvt_k(const float* __restrict__ X,
                                                  ushort_t* __restrict__ Y, int n8) {
  int i = blockIdx.x * 256 + threadIdx.x;
  if (i >= n8) return;
  const float4* in4 = (const float4*)X;
  float4 a = in4[2 * i], b = in4[2 * i + 1];
  uint4 o;
  o.x = pack2bf(a.x, a.y); o.y = pack2bf(a.z, a.w);
  o.z = pack2bf(b.x, b.y); o.w = pack2bf(b.z, b.w);
  ((uint4*)Y)[i] = o;
}

struct WC { const float* s; ushort_t* d; int K; };
struct WCA { WC w[6]; };
__global__ __launch_bounds__(128) void wcvt_k(WCA a) {
  const WC wc = a.w[blockIdx.x];
  const int k0 = blockIdx.y * 16;
  if (k0 >= wc.K) return;
  const int col = threadIdx.x;
  const int k1 = min(k0 + 16, wc.K);
  for (int k = k0; k < k1; k++)
    wc.d[(size_t)col * wc.K + k] = f2bf(wc.s[(size_t)k * 128 + col]);
}

// ---- CSR build: deterministic bucket partition, zero global atomics ----
__global__ __launch_bounds__(256) void sort_count_k(const int* __restrict__ dst,
                                                    int* __restrict__ tbl, int E) {
  __shared__ int cnt[NB];
  const int blk = blockIdx.x;
  for (int i = threadIdx.x; i < NB; i += 256) cnt[i] = 0;
  __syncthreads();
  const int e0 = blk * SCH, e1 = min(e0 + SCH, E);
  for (int e = e0 + threadIdx.x; e < e1; e += 256) atomicAdd(&cnt[dst[e] >> 8], 1);
  __syncthreads();
  for (int i = threadIdx.x; i < NB; i += 256) tbl[i * SNB + blk] = cnt[i];
}

__global__ __launch_bounds__(256) void bkt_total_k(const int* __restrict__ tbl,
                                                   int* __restrict__ total) {
  __shared__ int sm[256];
  const int b = blockIdx.x;
  const int t = threadIdx.x;
  sm[t] = (t < SNB) ? tbl[b * SNB + t] : 0;
  __syncthreads();
  for (int off = 128; off > 0; off >>= 1) {
    if (t < off) sm[t] += sm[t + off];
    __syncthreads();
  }
  if (t == 0) total[b] = sm[0];
}

__global__ __launch_bounds__(512) void bkt_scan_k(const int* __restrict__ total,
                                                  int* __restrict__ bktoff,
                                                  int* __restrict__ rowp, int n, int E) {
  __shared__ int sm[512];
  const int t = threadIdx.x;
  const int v = (t < NB) ? total[t] : 0;
  sm[t] = v;
  __syncthreads();
  for (int off = 1; off < 512; off <<= 1) {
    int u = (t >= off) ? sm[t - off] : 0;
    __syncthreads();
    sm[t] += u;
    __syncthreads();
  }
  if (t < NB) bktoff[t] = sm[t] - v;
  if (t == 0) { bktoff[NB] = E; rowp[n] = E; }
}

__global__ __launch_bounds__(256) void sort_offset_k(const int* __restrict__ tbl,
                                                     const int* __restrict__ bktoff,
                                                     int* __restrict__ off) {
  __shared__ int sm[256];
  const int b = blockIdx.x;
  const int t = threadIdx.x;
  const int v = (t < SNB) ? tbl[b * SNB + t] : 0;
  sm[t] = v;
  __syncthreads();
  for (int o = 1; o < 256; o <<= 1) {
    int u = (t >= o) ? sm[t - o] : 0;
    __syncthreads();
    sm[t] += u;
    __syncthreads();
  }
  if (t < SNB) off[b * SNB + t] = bktoff[b] + sm[t] - v;
}

__global__ __launch_bounds__(256) void sort_place_k(const int* __restrict__ src,
                                                    const int* __restrict__ dst,
                                                    const int* __restrict__ off,
                                                    uint_t* __restrict__ ebuf, int E) {
  __shared__ int pos[NB];
  const int blk = blockIdx.x;
  for (int i = threadIdx.x; i < NB; i += 256) pos[i] = off[i * SNB + blk];
  __syncthreads();
  const int e0 = blk * SCH, e1 = min(e0 + SCH, E);
  for (int e = e0 + threadIdx.x; e < e1; e += 256) {
    const int d = dst[e];
    const int p = atomicAdd(&pos[d >> 8], 1);
    ebuf[p] = (uint_t)src[e] | ((uint_t)(d & 255) << 17);
  }
}

__global__ __launch_bounds__(256) void bucket_fill2_k(const uint_t* __restrict__ ebuf,
                                                      const int* __restrict__ bktoff,
                                                      int* __restrict__ rowp,
                                                      float* __restrict__ dis,
                                                      int* __restrict__ esrc, int n) {
  __shared__ int hist[256];
  __shared__ int scn[256];
  const int b = blockIdx.x;
  const int t = threadIdx.x;
  const int r0 = b << 8;
  const int base = bktoff[b];
  const int end = bktoff[b + 1];
  hist[t] = 0;
  __syncthreads();
  for (int i = base + t; i < end; i += 256)
    atomicAdd(&hist[ebuf[i] >> 17], 1);
  __syncthreads();
  const int d = hist[t];
  scn[t] = d;
  __syncthreads();
  for (int off = 1; off < 256; off <<= 1) {
    int u = (t >= off) ? scn[t - off] : 0;
    __syncthreads();
    scn[t] += u;
    __syncthreads();
  }
  const int excl = scn[t] - d;
  const int r = r0 + t;
  if (r < n) {
    rowp[r] = base + excl;
    dis[r] = (d > 0) ? rsqrtf((float)d) : 0.f;
  }
  __syncthreads();
  hist[t] = excl;  // reuse as cursors
  __syncthreads();
  for (int i = base + t; i < end; i += 256) {
    const uint_t v = ebuf[i];
    const int rl = (int)(v >> 17);
    const int p = atomicAdd(&hist[rl], 1);
    esrc[base + p] = (int)(v & 0x1FFFFu);
  }
}

// ---------------------------------------------------------------- MFMA GEMM (branch-paired)
// blockIdx.y selects branch pointer set (uniform -> scalar loads from kernarg).
// A+B staged in LDS (SWZ 256B rows), epilogue fp32-bounced for coalesced stores.
struct GP {
  const ushort_t* X0[2]; const ushort_t* X1[2]; const ushort_t* X2[2];
  const ushort_t* Wt[2]; const float* bias[2];
  float* Yf[2]; ushort_t* Yb[2];
};
#define SWZ(base, row, byte) ((char*)(base) + (((row)*256 + (byte)) ^ (((row)&7) << 4)))
#define FST 130
__global__ __launch_bounds__(256) void gemm_pair_k(GP gp, int nrows, int nseg, int act) {
  __shared__ ushort_t smem[128 * FST * 2];  // 66560B; stage uses first 64KB
  ushort_t* sA = smem;
  ushort_t* sB = smem + 128 * 128;
  const int br = blockIdx.y;
  const ushort_t* X0 = gp.X0[br];
  const ushort_t* X1 = gp.X1[br];
  const ushort_t* X2 = gp.X2[br];
  const ushort_t* Wt = gp.Wt[br];
  const float* bias = gp.bias[br];
  float* Yf = gp.Yf[br];
  ushort_t* Yb = gp.Yb[br];

  const int t = threadIdx.x;
  const int wave = t >> 6;
  const int lane = t & 63;
  const int lane15 = lane & 15;
  const int lgrp = lane >> 4;  // 0..3
  const int row0 = blockIdx.x * 128;
  const int Ktot = nseg * 128;

  const int tr = t >> 1;
  const int th = (t & 1) * 64;
  const int ra = min(row0 + tr, nrows - 1);
  const int wb = th * 2;

  f32x4 acc[2][8];
#pragma unroll
  for (int m = 0; m < 2; m++)
#pragma unroll
    for (int f = 0; f < 8; f++) acc[m][f] = (f32x4)0.f;

  for (int seg = 0; seg < nseg; seg++) {
    const ushort_t* Xp = (seg == 0) ? X0 : ((seg == 1) ? X1 : X2);
    const ushort_t* Ap = Xp + (size_t)ra * 128 + th;
    const ushort_t* Bp = Wt + (size_t)tr * Ktot + (seg << 7) + th;
    const uint4 a0 = *(const uint4*)(Ap + 0);
    const uint4 a1 = *(const uint4*)(Ap + 8);
    const uint4 a2 = *(const uint4*)(Ap + 16);
    const uint4 a3 = *(const uint4*)(Ap + 24);
    const uint4 a4 = *(const uint4*)(Ap + 32);
    const uint4 a5 = *(const uint4*)(Ap + 40);
    const uint4 a6 = *(const uint4*)(Ap + 48);
    const uint4 a7 = *(const uint4*)(Ap + 56);
    const uint4 b0 = *(const uint4*)(Bp + 0);
    const uint4 b1 = *(const uint4*)(Bp + 8);
    const uint4 b2 = *(const uint4*)(Bp + 16);
    const uint4 b3 = *(const uint4*)(Bp + 24);
    const uint4 b4 = *(const uint4*)(Bp + 32);
    const uint4 b5 = *(const uint4*)(Bp + 40);
    const uint4 b6 = *(const uint4*)(Bp + 48);
    const uint4 b7 = *(const uint4*)(Bp + 56);
    __syncthreads();
    *(uint4*)SWZ(sA, tr, wb + 0) = a0;
    *(uint4*)SWZ(sA, tr, wb + 16) = a1;
    *(uint4*)SWZ(sA, tr, wb + 32) = a2;
    *(uint4*)SWZ(sA, tr, wb + 48) = a3;
    *(uint4*)SWZ(sA, tr, wb + 64) = a4;
    *(uint4*)SWZ(sA, tr, wb + 80) = a5;
    *(uint4*)SWZ(sA, tr, wb + 96) = a6;
    *(uint4*)SWZ(sA, tr, wb + 112) = a7;
    *(uint4*)SWZ(sB, tr, wb + 0) = b0;
    *(uint4*)SWZ(sB, tr, wb + 16) = b1;
    *(uint4*)SWZ(sB, tr, wb + 32) = b2;
    *(uint4*)SWZ(sB, tr, wb + 48) = b3;
    *(uint4*)SWZ(sB, tr, wb + 64) = b4;
    *(uint4*)SWZ(sB, tr, wb + 80) = b5;
    *(uint4*)SWZ(sB, tr, wb + 96) = b6;
    *(uint4*)SWZ(sB, tr, wb + 112) = b7;
    __syncthreads();
#pragma unroll
    for (int kk = 0; kk < 4; kk++) {
      const int cb = kk * 64 + lgrp * 16;
      const int rA0 = wave * 32 + lane15;
      bf16x8 av0 = *(const bf16x8*)SWZ(sA, rA0, cb);
      bf16x8 av1 = *(const bf16x8*)SWZ(sA, rA0 + 16, cb);
#pragma unroll
      for (int f = 0; f < 8; f++) {
        bf16x8 wv = *(const bf16x8*)SWZ(sB, f * 16 + lane15, cb);
        acc[0][f] = __builtin_amdgcn_mfma_f32_16x16x32_bf16(av0, wv, acc[0][f], 0, 0, 0);
        acc[1][f] = __builtin_amdgcn_mfma_f32_16x16x32_bf16(av1, wv, acc[1][f], 0, 0, 0);
      }
    }
  }

  // ---- epilogue: bounce acc through LDS for coalesced stores ----
  __syncthreads();
  float* fb = (float*)smem;
  const int row0w = wave * 32;
#pragma unroll
  for (int m = 0; m < 2; m++)
#pragma unroll
    for (int f = 0; f < 8; f++)
#pragma unroll
      for (int j = 0; j < 4; j++)
        fb[(row0w + m * 16 + lgrp * 4 + j) * FST + f * 16 + lane15] = acc[m][f][j];
  __syncthreads();
  const int rowg = row0 + tr;
  if (rowg < nrows) {
    const float* rp = fb + tr * FST + th;
    if (Yf) {
      float* yp = Yf + (size_t)rowg * 128 + th;
#pragma unroll
      for (int q = 0; q < 16; q++) {
        float4 v = ((const float4*)rp)[q];
        if (bias) {
          const float4 bv = ((const float4*)(bias + th))[q];
          v.x += bv.x; v.y += bv.y; v.z += bv.z; v.w += bv.w;
        }
        if (act == 1) {
          v.x = v.x > 0.f ? v.x : SLOPE * v.x; v.y = v.y > 0.f ? v.y : SLOPE * v.y;
          v.z = v.z > 0.f ? v.z : SLOPE * v.z; v.w = v.w > 0.f ? v.w : SLOPE * v.w;
        } else if (act == 2) {
          v.x = v.x > 0.f ? v.x : 0.f; v.y = v.y > 0.f ? v.y : 0.f;
          v.z = v.z > 0.f ? v.z : 0.f; v.w = v.w > 0.f ? v.w : 0.f;
        }
        ((float4*)yp)[q] = v;
      }
    } else {
      ushort_t* yp = Yb + (size_t)rowg * 128 + th;
#pragma unroll
      for (int q = 0; q < 8; q++) {
        float4 v0 = ((const float4*)rp)[2 * q];
        float4 v1 = ((const float4*)rp)[2 * q + 1];
        if (bias) {
          const float4 c0 = ((const float4*)(bias + th))[2 * q];
          const float4 c1 = ((const float4*)(bias + th))[2 * q + 1];
          v0.x += c0.x; v0.y += c0.y; v0.z += c0.z; v0.w += c0.w;
          v1.x += c1.x; v1.y += c1.y; v1.z += c1.z; v1.w += c1.w;
        }
        if (act == 1) {
          v0.x = v0.x > 0.f ? v0.x : SLOPE * v0.x; v0.y = v0.y > 0.f ? v0.y : SLOPE * v0.y;
          v0.z = v0.z > 0.f ? v0.z : SLOPE * v0.z; v0.w = v0.w > 0.f ? v0.w : SLOPE * v0.w;
          v1.x = v1.x > 0.f ? v1.x : SLOPE * v1.x; v1.y = v1.y > 0.f ? v1.y : SLOPE * v1.y;
          v1.z = v1.z > 0.f ? v1.z : SLOPE * v1.z; v1.w = v1.w > 0.f ? v1.w : SLOPE * v1.w;
        } else if (act == 2) {
          v0.x = v0.x > 0.f ? v0.x : 0.f; v0.y = v0.y > 0.f ? v0.y : 0.f;
          v0.z = v0.z > 0.f ? v0.z : 0.f; v0.w = v0.w > 0.f ? v0.w : 0.f;
          v1.x = v1.x > 0.f ? v1.x : 0.f; v1.y = v1.y > 0.f ? v1.y : 0.f;
          v1.z = v1.z > 0.f ? v1.z : 0.f; v1.w = v1.w > 0.f ? v1.w : 0.f;
        }
        uint4 o;
        o.x = pack2bf(v0.x, v0.y); o.y = pack2bf(v0.z, v0.w);
        o.z = pack2bf(v1.x, v1.y); o.w = pack2bf(v1.z, v1.w);
        ((uint4*)yp)[q] = o;
      }
    }
  }
}

// ---------------------------------------------------------------- gather (branch-paired)
struct GA {
  const ushort_t* xw[2]; const int* rowp[2]; const int* esrc[2];
  const float* dis[2]; const float* bias[2]; ushort_t* out[2];
};
__global__ __launch_bounds__(256) void gather_pair_k(GA g, int nrows) {
  const int br = blockIdx.y;
  const ushort_t* xw = g.xw[br];
  const int* rowp = g.rowp[br];
  const int* esrc = g.esrc[br];
  const float* dis = g.dis[br];
  const float* bias = g.bias[br];
  ushort_t* out = g.out[br];

  const int lane = threadIdx.x & 63;
  const int row = (blockIdx.x * blockDim.x + threadIdx.x) >> 6;
  if (row >= nrows) return;
  const int slot = lane >> 4;
  const int ch = lane & 15;
  const int start = rowp[row];
  const int end = rowp[row + 1];
  const float dr = dis[row];

  float a0 = 0.f, a1 = 0.f, a2 = 0.f, a3 = 0.f, a4 = 0.f, a5 = 0.f, a6 = 0.f, a7 = 0.f;
  for (int j = start + slot; j < end; j += 8) {
    const int s1 = esrc[j];
    const int j2 = j + 4;
    const bool h2 = j2 < end;
    const int s2 = h2 ? esrc[j2] : s1;
    const float w1 = dis[s1];
    const float w2 = h2 ? dis[s2] : 0.f;
    const uint4 v1 = *(const uint4*)(xw + (size_t)s1 * 128 + ch * 8);
    const uint4 v2 = *(const uint4*)(xw + (size_t)s2 * 128 + ch * 8);
    a0 += w1 * __uint_as_float(v1.x << 16) + w2 * __uint_as_float(v2.x << 16);
    a1 += w1 * __uint_as_float(v1.x & 0xFFFF0000u) + w2 * __uint_as_float(v2.x & 0xFFFF0000u);
    a2 += w1 * __uint_as_float(v1.y << 16) + w2 * __uint_as_float(v2.y << 16);
    a3 += w1 * __uint_as_float(v1.y & 0xFFFF0000u) + w2 * __uint_as_float(v2.y & 0xFFFF0000u);
    a4 += w1 * __uint_as_float(v1.z << 16) + w2 * __uint_as_float(v2.z << 16);
    a5 += w1 * __uint_as_float(v1.z & 0xFFFF0000u) + w2 * __uint_as_float(v2.z & 0xFFFF0000u);
    a6 += w1 * __uint_as_float(v1.w << 16) + w2 * __uint_as_float(v2.w << 16);
    a7 += w1 * __uint_as_float(v1.w & 0xFFFF0000u) + w2 * __uint_as_float(v2.w & 0xFFFF0000u);
  }
  a0 += __shfl_xor(a0, 16, 64); a1 += __shfl_xor(a1, 16, 64);
  a2 += __shfl_xor(a2, 16, 64); a3 += __shfl_xor(a3, 16, 64);
  a4 += __shfl_xor(a4, 16, 64); a5 += __shfl_xor(a5, 16, 64);
  a6 += __shfl_xor(a6, 16, 64); a7 += __shfl_xor(a7, 16, 64);
  a0 += __shfl_xor(a0, 32, 64); a1 += __shfl_xor(a1, 32, 64);
  a2 += __shfl_xor(a2, 32, 64); a3 += __shfl_xor(a3, 32, 64);
  a4 += __shfl_xor(a4, 32, 64); a5 += __shfl_xor(a5, 32, 64);
  a6 += __shfl_xor(a6, 32, 64); a7 += __shfl_xor(a7, 32, 64);

  if (slot == 0) {
    const float4 b0 = *(const float4*)(bias + ch * 8);
    const float4 b1 = *(const float4*)(bias + ch * 8 + 4);
    float o0 = dr * a0 + b0.x, o1 = dr * a1 + b0.y;
    float o2 = dr * a2 + b0.z, o3 = dr * a3 + b0.w;
    float o4 = dr * a4 + b1.x, o5 = dr * a5 + b1.y;
    float o6 = dr * a6 + b1.z, o7 = dr * a7 + b1.w;
    o0 = o0 > 0.f ? o0 : SLOPE * o0; o1 = o1 > 0.f ? o1 : SLOPE * o1;
    o2 = o2 > 0.f ? o2 : SLOPE * o2; o3 = o3 > 0.f ? o3 : SLOPE * o3;
    o4 = o4 > 0.f ? o4 : SLOPE * o4; o5 = o5 > 0.f ? o5 : SLOPE * o5;
    o6 = o6 > 0.f ? o6 : SLOPE * o6; o7 = o7 > 0.f ? o7 : SLOPE * o7;
    uint4 o;
    o.x = pack2bf(o0, o1); o.y = pack2bf(o2, o3);
    o.z = pack2bf(o4, o5); o.w = pack2bf(o6, o7);
    *(uint4*)(out + (size_t)row * 128 + ch * 8) = o;
  }
}

// ---------------------------------------------------------------- batchnorm (paired)
__global__ __launch_bounds__(256) void bn_stats_pair_k(const ushort_t* __restrict__ XS,
                                                       const ushort_t* __restrict__ XR,
                                                       float* __restrict__ sums,
                                                       float* __restrict__ sumsq, int nrows) {
  __shared__ float ls[256], lq[256];
  const int br = blockIdx.y;
  const ushort_t* X = br ? XR : XS;
  const int t = threadIdx.x;
  const int c = t & 127;
  const int h = t >> 7;
  const int r0 = blockIdx.x * 256;
  const int r1 = min(r0 + 256, nrows);
  float s = 0.f, q = 0.f;
  for (int r = r0 + h; r < r1; r += 2) {
    float v = bf2f(X[(size_t)r * 128 + c]);
    s += v;
    q += v * v;
  }
  ls[t] = s;
  lq[t] = q;
  __syncthreads();
  if (t < 128) {
    s = ls[t] + ls[t + 128];
    q = lq[t] + lq[t + 128];
    atomicAdd(&sums[br * 128 + c], s);
    atomicAdd(&sumsq[br * 128 + c], q);
  }
}

// both branches: t<128 -> S, t>=128 -> R
__global__ __launch_bounds__(256) void bn_finalize_k(const float* __restrict__ sums,
                                                     const float* __restrict__ sumsq,
                                                     const float* __restrict__ gS,
                                                     const float* __restrict__ beS,
                                                     const float* __restrict__ gR,
                                                     const float* __restrict__ beR,
                                                     float* __restrict__ scl,
                                                     float* __restrict__ sht) {
  int t = threadIdx.x;  // 0..255
  int c = t & 127;
  int br = t >> 7;
  float mu = sums[t] * (1.f / (float)NN);
  float var = sumsq[t] * (1.f / (float)NN) - mu * mu;
  float gv = br ? gR[c] : gS[c];
  float bv = br ? beR[c] : beS[c];
  float s = gv * rsqrtf(var + FEPS);
  scl[t] = s;
  sht[t] = bv - mu * s;
}

// fold BN affine into head weight; scl/sht are [2][128] (S then R)
__global__ __launch_bounds__(128) void fold_head_k(const float* __restrict__ W,
                                                   const float* __restrict__ b,
                                                   const float* __restrict__ scl,
                                                   const float* __restrict__ sht,
                                                   ushort_t* __restrict__ Wf,
                                                   float* __restrict__ bf) {
  const int col = threadIdx.x;
  float acc = b[col];
  for (int k = 0; k < 256; k++) {
    const float w = W[(size_t)k * 128 + col];
    acc += sht[k] * w;
    Wf[(size_t)col * 256 + k] = f2bf(scl[k] * w);
  }
  bf[col] = acc;
}

// ---------------------------------------------------------------- launch
extern "C" void kernel_launch(void* const* d_in, const int* in_sizes, int n_in,
                              void* d_out, int out_size, void* d_ws, size_t ws_size,
                              hipStream_t stream) {
  const float* feature = (const float*)d_in[0];
  const int* sen_edge = (const int*)d_in[1];
  const int* res_edge = (const int*)d_in[2];
  const float* W_sen1 = (const float*)d_in[3];
  const float* b_sen1 = (const float*)d_in[4];
  const float* W_sen2 = (const float*)d_in[5];
  const float* b_sen2 = (const float*)d_in[6];
  const float* W_senfc = (const float*)d_in[7];
  const float* b_senfc = (const float*)d_in[8];
  const float* g_sen = (const float*)d_in[9];
  const float* be_sen = (const float*)d_in[10];
  const float* W_res1 = (const float*)d_in[11];
  const float* b_res1 = (const float*)d_in[12];
  const float* W_res2 = (const float*)d_in[13];
  const float* b_res2 = (const float*)d_in[14];
  const float* W_resfc = (const float*)d_in[15];
  const float* b_resfc = (const float*)d_in[16];
  const float* g_res = (const float*)d_in[17];
  const float* be_res = (const float*)d_in[18];
  const float* W_cell = (const float*)d_in[19];
  const float* b_cell = (const float*)d_in[20];
  const float* W_drug = (const float*)d_in[21];
  const float* b_drug = (const float*)d_in[22];
  float* out = (float*)d_out;

  const size_t NF = (size_t)NN * 128;
  char* wsb = (char*)d_ws;
  ushort_t* featb = (ushort_t*)wsb;                 // NF bf16 each
  ushort_t* xwb0 = featb + NF;                      // doubles as xall0
  ushort_t* xwb1 = xwb0 + NF;                       // doubles as xall1
  ushort_t* x1b0 = xwb1 + NF;
  ushort_t* x1b1 = x1b0 + NF;
  ushort_t* x2b0 = x1b1 + NF;
  ushort_t* x2b1 = x2b0 + NF;
  ushort_t* wt = x2b1 + NF;                         // weight pool
  ushort_t* W1tS = wt;                              // 128*128
  ushort_t* W2tS = W1tS + 128 * 128;
  ushort_t* WfctS = W2tS + 128 * 128;               // 128*384
  ushort_t* W1tR = WfctS + 128 * 384;
  ushort_t* W2tR = W1tR + 128 * 128;
  ushort_t* WfctR = W2tR + 128 * 128;
  ushort_t* Wcellf = WfctR + 128 * 384;             // 128*256 (folded)
  ushort_t* Wdrugf = Wcellf + 128 * 256;
  float* dis0 = (float*)(Wdrugf + 128 * 256);       // NN each
  float* dis1 = dis0 + NN;
  int* rowp0 = (int*)(dis1 + NN);                   // NN+1 each
  int* rowp1 = rowp0 + (NN + 1);
  int* esrc0 = rowp1 + (NN + 1);                    // EE each
  int* esrc1 = esrc0 + EE;
  uint_t* ebuf = (uint_t*)(esrc1 + EE);             // EE (shared scratch)
  int* tbl = (int*)(ebuf + EE);                     // NB*SNB (shared)
  int* off = tbl + NB * SNB;                        // NB*SNB (shared)
  int* total = off + NB * SNB;                      // NB
  int* bktoff = total + NB;                         // NB+1
  float* sums = (float*)(bktoff + NB + 1);          // 2*128
  float* sumsq = sums + 256;                        // 2*128
  float* scl = sumsq + 256;                         // 2*128 (S,R)
  float* sht = scl + 256;                           // 2*128
  float* bcellf = sht + 256;
  float* bdrugf = bcellf + 128;

  const int MG = (NN + 127) / 128;          // 782
  const int GATH_N = (NN * 64 + 255) / 256; // 25000
  const int STAT_N = (NN + 255) / 256;      // 391

  feat_cvt_k<<<(int)(NF / 8 + 255) / 256, 256, 0, stream>>>(feature, featb, (int)(NF / 8));
  WCA wa;
  wa.w[0] = {W_sen1, W1tS, 128};  wa.w[1] = {W_sen2, W2tS, 128};
  wa.w[2] = {W_senfc, WfctS, 384}; wa.w[3] = {W_res1, W1tR, 128};
  wa.w[4] = {W_res2, W2tR, 128};  wa.w[5] = {W_resfc, WfctR, 384};
  wcvt_k<<<dim3(6, 24), 128, 0, stream>>>(wa);

  // CSR build per branch (shared scratch, per-branch outputs)
  const int* edges[2] = {sen_edge, res_edge};
  int* rowps[2] = {rowp0, rowp1};
  float* diss[2] = {dis0, dis1};
  int* esrcs[2] = {esrc0, esrc1};
  for (int b = 0; b < 2; b++) {
    const int* src = edges[b];
    const int* dst = edges[b] + EE;
    sort_count_k<<<SNB, 256, 0, stream>>>(dst, tbl, EE);
    bkt_total_k<<<NB, 256, 0, stream>>>(tbl, total);
    bkt_scan_k<<<1, 512, 0, stream>>>(total, bktoff, rowps[b], NN, EE);
    sort_offset_k<<<NB, 256, 0, stream>>>(tbl, bktoff, off);
    sort_place_k<<<SNB, 256, 0, stream>>>(src, dst, off, ebuf, EE);
    bucket_fill2_k<<<NB, 256, 0, stream>>>(ebuf, bktoff, rowps[b], diss[b], esrcs[b], NN);
  }

  // paired pipeline
  GP g1 = {};
  g1.X0[0] = featb; g1.X0[1] = featb;
  g1.Wt[0] = W1tS; g1.Wt[1] = W1tR;
  g1.Yb[0] = xwb0; g1.Yb[1] = xwb1;
  gemm_pair_k<<<dim3(MG, 2), 256, 0, stream>>>(g1, NN, 1, 0);

  GA ga = {};
  ga.rowp[0] = rowp0; ga.rowp[1] = rowp1;
  ga.esrc[0] = esrc0; ga.esrc[1] = esrc1;
  ga.dis[0] = dis0; ga.dis[1] = dis1;
  ga.xw[0] = xwb0; ga.xw[1] = xwb1;
  ga.bias[0] = b_sen1; ga.bias[1] = b_res1;
  ga.out[0] = x1b0; ga.out[1] = x1b1;
  gather_pair_k<<<dim3(GATH_N, 2), 256, 0, stream>>>(ga, NN);

  GP g2 = {};
  g2.X0[0] = x1b0; g2.X0[1] = x1b1;
  g2.Wt[0] = W2tS; g2.Wt[1] = W2tR;
  g2.Yb[0] = xwb0; g2.Yb[1] = xwb1;
  gemm_pair_k<<<dim3(MG, 2), 256, 0, stream>>>(g2, NN, 1, 0);

  ga.bias[0] = b_sen2; ga.bias[1] = b_res2;
  ga.out[0] = x2b0; ga.out[1] = x2b1;
  gather_pair_k<<<dim3(GATH_N, 2), 256, 0, stream>>>(ga, NN);

  // fc: writes xall into the (now dead) xwb buffers
  GP gf = {};
  gf.X0[0] = featb; gf.X0[1] = featb;
  gf.X1[0] = x1b0; gf.X1[1] = x1b1;
  gf.X2[0] = x2b0; gf.X2[1] = x2b1;
  gf.Wt[0] = WfctS; gf.Wt[1] = WfctR;
  gf.bias[0] = b_senfc; gf.bias[1] = b_resfc;
  gf.Yb[0] = xwb0; gf.Yb[1] = xwb1;
  gemm_pair_k<<<dim3(MG, 2), 256, 0, stream>>>(gf, NN, 3, 2);

  (void)hipMemsetAsync(sums, 0, 2 * 256 * sizeof(float), stream);
  bn_stats_pair_k<<<dim3(STAT_N, 2), 256, 0, stream>>>(xwb0, xwb1, sums, sumsq, NN);
  bn_finalize_k<<<1, 256, 0, stream>>>(sums, sumsq, g_sen, be_sen, g_res, be_res, scl, sht);

  fold_head_k<<<1, 128, 0, stream>>>(W_cell, b_cell, scl, sht, Wcellf, bcellf);
  fold_head_k<<<1, 128, 0, stream>>>(W_drug, b_drug, scl, sht, Wdrugf, bdrugf);
  const int MGC = (NCELL + 127) / 128;
  const int MGD = (NDRUG + 127) / 128;
  GP gc = {};
  gc.X0[0] = xwb0; gc.X1[0] = xwb1;
  gc.Wt[0] = Wcellf; gc.bias[0] = bcellf; gc.Yf[0] = out;
  gemm_pair_k<<<dim3(MGC, 1), 256, 0, stream>>>(gc, NCELL, 2, 2);
  float* outD = out + (size_t)NCELL * 128;
  GP gd = {};
  gd.X0[0] = xwb0 + (size_t)NCELL * 128; gd.X1[0] = xwb1 + (size_t)NCELL * 128;
  gd.Wt[0] = Wdrugf; gd.bias[0] = bdrugf; gd.Yf[0] = outD;
  gemm_pair_k<<<dim3(MGD, 1), 256, 0, stream>>>(gd, NDRUG, 2, 2);
}

// Round 19
// 647.490 us; speedup vs baseline: 1.2822x; 1.1219x over previous
//
#include <hip/hip_runtime.h>

#define NN 100000
#define NCELL 40000
#define NDRUG 60000
#define EE 1600000
#define FEPS 1e-5f
#define SLOPE 0.2f
#define NB 391    // dst-buckets (256 rows each)
#define SCH 8192  // edges per sort block
#define SNB 196   // ceil(EE/SCH)

typedef unsigned short ushort_t;
typedef unsigned int uint_t;
typedef __attribute__((ext_vector_type(8))) __bf16 bf16x8;
typedef __attribute__((ext_vector_type(4))) float f32x4;

__device__ __forceinline__ ushort_t f2bf(float x) {
  uint_t u = __float_as_uint(x);
  u = (u + 0x7FFFu + ((u >> 16) & 1u)) >> 16;  // RNE
  return (ushort_t)u;
}
__device__ __forceinline__ uint_t pack2bf(float a, float b) {
  return (uint_t)f2bf(a) | ((uint_t)f2bf(b) << 16);
}
__device__ __forceinline__ float bf2f(ushort_t x) {
  return __uint_as_float(((uint_t)x) << 16);
}

// ---------------------------------------------------------------- converts
__global__ __launch_bounds__(256) void feat_cvt_k(const float* __restrict__ X,
                                                  ushort_t* __restrict__ Y, int n8) {
  int i = blockIdx.x * 256 + threadIdx.x;
  if (i >= n8) return;
  const float4* in4 = (const float4*)X;
  float4 a = in4[2 * i], b = in4[2 * i + 1];
  uint4 o;
  o.x = pack2bf(a.x, a.y); o.y = pack2bf(a.z, a.w);
  o.z = pack2bf(b.x, b.y); o.w = pack2bf(b.z, b.w);
  ((uint4*)Y)[i] = o;
}

struct WC { const float* s; ushort_t* d; int K; };
struct WCA { WC w[6]; };
__global__ __launch_bounds__(128) void wcvt_k(WCA a) {
  const WC wc = a.w[blockIdx.x];
  const int k0 = blockIdx.y * 16;
  if (k0 >= wc.K) return;
  const int col = threadIdx.x;
  const int k1 = min(k0 + 16, wc.K);
  for (int k = k0; k < k1; k++)
    wc.d[(size_t)col * wc.K + k] = f2bf(wc.s[(size_t)k * 128 + col]);
}

// ---- CSR build (branch-paired via blockIdx.y): zero global atomics ----
struct CS {
  const int* src[2]; const int* dst[2];
  int* tbl[2]; int* off[2]; int* total[2]; int* bktoff[2];
  int* rowp[2]; float* dis[2]; int* esrc[2]; uint_t* ebuf[2];
};

__global__ __launch_bounds__(256) void sort_count_k(CS cs, int E) {
  __shared__ int cnt[NB];
  const int br = blockIdx.y;
  const int* dst = cs.dst[br];
  int* tbl = cs.tbl[br];
  const int blk = blockIdx.x;
  for (int i = threadIdx.x; i < NB; i += 256) cnt[i] = 0;
  __syncthreads();
  const int e0 = blk * SCH, e1 = min(e0 + SCH, E);
  for (int e = e0 + threadIdx.x; e < e1; e += 256) atomicAdd(&cnt[dst[e] >> 8], 1);
  __syncthreads();
  for (int i = threadIdx.x; i < NB; i += 256) tbl[i * SNB + blk] = cnt[i];
}

__global__ __launch_bounds__(256) void bkt_total_k(CS cs) {
  __shared__ int sm[256];
  const int br = blockIdx.y;
  const int* tbl = cs.tbl[br];
  const int b = blockIdx.x;
  const int t = threadIdx.x;
  sm[t] = (t < SNB) ? tbl[b * SNB + t] : 0;
  __syncthreads();
  for (int off = 128; off > 0; off >>= 1) {
    if (t < off) sm[t] += sm[t + off];
    __syncthreads();
  }
  if (t == 0) cs.total[br][b] = sm[0];
}

__global__ __launch_bounds__(512) void bkt_scan_k(CS cs, int n, int E) {
  __shared__ int sm[512];
  const int br = blockIdx.y;
  const int* total = cs.total[br];
  int* bktoff = cs.bktoff[br];
  const int t = threadIdx.x;
  const int v = (t < NB) ? total[t] : 0;
  sm[t] = v;
  __syncthreads();
  for (int off = 1; off < 512; off <<= 1) {
    int u = (t >= off) ? sm[t - off] : 0;
    __syncthreads();
    sm[t] += u;
    __syncthreads();
  }
  if (t < NB) bktoff[t] = sm[t] - v;
  if (t == 0) { bktoff[NB] = E; cs.rowp[br][n] = E; }
}

__global__ __launch_bounds__(256) void sort_offset_k(CS cs) {
  __shared__ int sm[256];
  const int br = blockIdx.y;
  const int* tbl = cs.tbl[br];
  const int b = blockIdx.x;
  const int t = threadIdx.x;
  const int v = (t < SNB) ? tbl[b * SNB + t] : 0;
  sm[t] = v;
  __syncthreads();
  for (int o = 1; o < 256; o <<= 1) {
    int u = (t >= o) ? sm[t - o] : 0;
    __syncthreads();
    sm[t] += u;
    __syncthreads();
  }
  if (t < SNB) cs.off[br][b * SNB + t] = cs.bktoff[br][b] + sm[t] - v;
}

__global__ __launch_bounds__(256) void sort_place_k(CS cs, int E) {
  __shared__ int pos[NB];
  const int br = blockIdx.y;
  const int* src = cs.src[br];
  const int* dst = cs.dst[br];
  uint_t* ebuf = cs.ebuf[br];
  const int blk = blockIdx.x;
  for (int i = threadIdx.x; i < NB; i += 256) pos[i] = cs.off[br][i * SNB + blk];
  __syncthreads();
  const int e0 = blk * SCH, e1 = min(e0 + SCH, E);
  for (int e = e0 + threadIdx.x; e < e1; e += 256) {
    const int d = dst[e];
    const int p = atomicAdd(&pos[d >> 8], 1);
    ebuf[p] = (uint_t)src[e] | ((uint_t)(d & 255) << 17);
  }
}

__global__ __launch_bounds__(256) void bucket_fill2_k(CS cs, int n) {
  __shared__ int hist[256];
  __shared__ int scn[256];
  const int br = blockIdx.y;
  const uint_t* ebuf = cs.ebuf[br];
  const int* bktoff = cs.bktoff[br];
  const int b = blockIdx.x;
  const int t = threadIdx.x;
  const int r0 = b << 8;
  const int base = bktoff[b];
  const int end = bktoff[b + 1];
  hist[t] = 0;
  __syncthreads();
  for (int i = base + t; i < end; i += 256)
    atomicAdd(&hist[ebuf[i] >> 17], 1);
  __syncthreads();
  const int d = hist[t];
  scn[t] = d;
  __syncthreads();
  for (int off = 1; off < 256; off <<= 1) {
    int u = (t >= off) ? scn[t - off] : 0;
    __syncthreads();
    scn[t] += u;
    __syncthreads();
  }
  const int excl = scn[t] - d;
  const int r = r0 + t;
  if (r < n) {
    cs.rowp[br][r] = base + excl;
    cs.dis[br][r] = (d > 0) ? rsqrtf((float)d) : 0.f;
  }
  __syncthreads();
  hist[t] = excl;  // reuse as cursors
  __syncthreads();
  for (int i = base + t; i < end; i += 256) {
    const uint_t v = ebuf[i];
    const int rl = (int)(v >> 17);
    const int p = atomicAdd(&hist[rl], 1);
    cs.esrc[br][base + p] = (int)(v & 0x1FFFFu);
  }
}

// ---------------------------------------------------------------- MFMA GEMM (branch-paired)
struct GP {
  const ushort_t* X0[2]; const ushort_t* X1[2]; const ushort_t* X2[2];
  const ushort_t* Wt[2]; const float* bias[2];
  float* Yf[2]; ushort_t* Yb[2];
};
#define SWZ(base, row, byte) ((char*)(base) + (((row)*256 + (byte)) ^ (((row)&7) << 4)))
#define FST 130
__global__ __launch_bounds__(256) void gemm_pair_k(GP gp, int nrows, int nseg, int act) {
  __shared__ ushort_t smem[128 * FST * 2];  // 66560B; stage uses first 64KB
  ushort_t* sA = smem;
  ushort_t* sB = smem + 128 * 128;
  const int br = blockIdx.y;
  const ushort_t* X0 = gp.X0[br];
  const ushort_t* X1 = gp.X1[br];
  const ushort_t* X2 = gp.X2[br];
  const ushort_t* Wt = gp.Wt[br];
  const float* bias = gp.bias[br];
  float* Yf = gp.Yf[br];
  ushort_t* Yb = gp.Yb[br];

  const int t = threadIdx.x;
  const int wave = t >> 6;
  const int lane = t & 63;
  const int lane15 = lane & 15;
  const int lgrp = lane >> 4;  // 0..3
  const int row0 = blockIdx.x * 128;
  const int Ktot = nseg * 128;

  const int tr = t >> 1;
  const int th = (t & 1) * 64;
  const int ra = min(row0 + tr, nrows - 1);
  const int wb = th * 2;

  f32x4 acc[2][8];
#pragma unroll
  for (int m = 0; m < 2; m++)
#pragma unroll
    for (int f = 0; f < 8; f++) acc[m][f] = (f32x4)0.f;

  for (int seg = 0; seg < nseg; seg++) {
    const ushort_t* Xp = (seg == 0) ? X0 : ((seg == 1) ? X1 : X2);
    const ushort_t* Ap = Xp + (size_t)ra * 128 + th;
    const ushort_t* Bp = Wt + (size_t)tr * Ktot + (seg << 7) + th;
    const uint4 a0 = *(const uint4*)(Ap + 0);
    const uint4 a1 = *(const uint4*)(Ap + 8);
    const uint4 a2 = *(const uint4*)(Ap + 16);
    const uint4 a3 = *(const uint4*)(Ap + 24);
    const uint4 a4 = *(const uint4*)(Ap + 32);
    const uint4 a5 = *(const uint4*)(Ap + 40);
    const uint4 a6 = *(const uint4*)(Ap + 48);
    const uint4 a7 = *(const uint4*)(Ap + 56);
    const uint4 b0 = *(const uint4*)(Bp + 0);
    const uint4 b1 = *(const uint4*)(Bp + 8);
    const uint4 b2 = *(const uint4*)(Bp + 16);
    const uint4 b3 = *(const uint4*)(Bp + 24);
    const uint4 b4 = *(const uint4*)(Bp + 32);
    const uint4 b5 = *(const uint4*)(Bp + 40);
    const uint4 b6 = *(const uint4*)(Bp + 48);
    const uint4 b7 = *(const uint4*)(Bp + 56);
    __syncthreads();
    *(uint4*)SWZ(sA, tr, wb + 0) = a0;
    *(uint4*)SWZ(sA, tr, wb + 16) = a1;
    *(uint4*)SWZ(sA, tr, wb + 32) = a2;
    *(uint4*)SWZ(sA, tr, wb + 48) = a3;
    *(uint4*)SWZ(sA, tr, wb + 64) = a4;
    *(uint4*)SWZ(sA, tr, wb + 80) = a5;
    *(uint4*)SWZ(sA, tr, wb + 96) = a6;
    *(uint4*)SWZ(sA, tr, wb + 112) = a7;
    *(uint4*)SWZ(sB, tr, wb + 0) = b0;
    *(uint4*)SWZ(sB, tr, wb + 16) = b1;
    *(uint4*)SWZ(sB, tr, wb + 32) = b2;
    *(uint4*)SWZ(sB, tr, wb + 48) = b3;
    *(uint4*)SWZ(sB, tr, wb + 64) = b4;
    *(uint4*)SWZ(sB, tr, wb + 80) = b5;
    *(uint4*)SWZ(sB, tr, wb + 96) = b6;
    *(uint4*)SWZ(sB, tr, wb + 112) = b7;
    __syncthreads();
#pragma unroll
    for (int kk = 0; kk < 4; kk++) {
      const int cb = kk * 64 + lgrp * 16;
      const int rA0 = wave * 32 + lane15;
      bf16x8 av0 = *(const bf16x8*)SWZ(sA, rA0, cb);
      bf16x8 av1 = *(const bf16x8*)SWZ(sA, rA0 + 16, cb);
#pragma unroll
      for (int f = 0; f < 8; f++) {
        bf16x8 wv = *(const bf16x8*)SWZ(sB, f * 16 + lane15, cb);
        acc[0][f] = __builtin_amdgcn_mfma_f32_16x16x32_bf16(av0, wv, acc[0][f], 0, 0, 0);
        acc[1][f] = __builtin_amdgcn_mfma_f32_16x16x32_bf16(av1, wv, acc[1][f], 0, 0, 0);
      }
    }
  }

  // ---- epilogue: bounce acc through LDS for coalesced stores ----
  __syncthreads();
  float* fb = (float*)smem;
  const int row0w = wave * 32;
#pragma unroll
  for (int m = 0; m < 2; m++)
#pragma unroll
    for (int f = 0; f < 8; f++)
#pragma unroll
      for (int j = 0; j < 4; j++)
        fb[(row0w + m * 16 + lgrp * 4 + j) * FST + f * 16 + lane15] = acc[m][f][j];
  __syncthreads();
  const int rowg = row0 + tr;
  if (rowg < nrows) {
    const float* rp = fb + tr * FST + th;
    if (Yf) {
      float* yp = Yf + (size_t)rowg * 128 + th;
#pragma unroll
      for (int q = 0; q < 16; q++) {
        float4 v = ((const float4*)rp)[q];
        if (bias) {
          const float4 bv = ((const float4*)(bias + th))[q];
          v.x += bv.x; v.y += bv.y; v.z += bv.z; v.w += bv.w;
        }
        if (act == 1) {
          v.x = v.x > 0.f ? v.x : SLOPE * v.x; v.y = v.y > 0.f ? v.y : SLOPE * v.y;
          v.z = v.z > 0.f ? v.z : SLOPE * v.z; v.w = v.w > 0.f ? v.w : SLOPE * v.w;
        } else if (act == 2) {
          v.x = v.x > 0.f ? v.x : 0.f; v.y = v.y > 0.f ? v.y : 0.f;
          v.z = v.z > 0.f ? v.z : 0.f; v.w = v.w > 0.f ? v.w : 0.f;
        }
        ((float4*)yp)[q] = v;
      }
    } else {
      ushort_t* yp = Yb + (size_t)rowg * 128 + th;
#pragma unroll
      for (int q = 0; q < 8; q++) {
        float4 v0 = ((const float4*)rp)[2 * q];
        float4 v1 = ((const float4*)rp)[2 * q + 1];
        if (bias) {
          const float4 c0 = ((const float4*)(bias + th))[2 * q];
          const float4 c1 = ((const float4*)(bias + th))[2 * q + 1];
          v0.x += c0.x; v0.y += c0.y; v0.z += c0.z; v0.w += c0.w;
          v1.x += c1.x; v1.y += c1.y; v1.z += c1.z; v1.w += c1.w;
        }
        if (act == 1) {
          v0.x = v0.x > 0.f ? v0.x : SLOPE * v0.x; v0.y = v0.y > 0.f ? v0.y : SLOPE * v0.y;
          v0.z = v0.z > 0.f ? v0.z : SLOPE * v0.z; v0.w = v0.w > 0.f ? v0.w : SLOPE * v0.w;
          v1.x = v1.x > 0.f ? v1.x : SLOPE * v1.x; v1.y = v1.y > 0.f ? v1.y : SLOPE * v1.y;
          v1.z = v1.z > 0.f ? v1.z : SLOPE * v1.z; v1.w = v1.w > 0.f ? v1.w : SLOPE * v1.w;
        } else if (act == 2) {
          v0.x = v0.x > 0.f ? v0.x : 0.f; v0.y = v0.y > 0.f ? v0.y : 0.f;
          v0.z = v0.z > 0.f ? v0.z : 0.f; v0.w = v0.w > 0.f ? v0.w : 0.f;
          v1.x = v1.x > 0.f ? v1.x : 0.f; v1.y = v1.y > 0.f ? v1.y : 0.f;
          v1.z = v1.z > 0.f ? v1.z : 0.f; v1.w = v1.w > 0.f ? v1.w : 0.f;
        }
        uint4 o;
        o.x = pack2bf(v0.x, v0.y); o.y = pack2bf(v0.z, v0.w);
        o.z = pack2bf(v1.x, v1.y); o.w = pack2bf(v1.z, v1.w);
        ((uint4*)yp)[q] = o;
      }
    }
  }
}

// ---------------------------------------------------------------- gather (branch-paired)
struct GA {
  const ushort_t* xw[2]; const int* rowp[2]; const int* esrc[2];
  const float* dis[2]; const float* bias[2]; ushort_t* out[2];
};
__global__ __launch_bounds__(256) void gather_pair_k(GA g, int nrows) {
  const int br = blockIdx.y;
  const ushort_t* xw = g.xw[br];
  const int* rowp = g.rowp[br];
  const int* esrc = g.esrc[br];
  const float* dis = g.dis[br];
  const float* bias = g.bias[br];
  ushort_t* out = g.out[br];

  const int lane = threadIdx.x & 63;
  const int row = (blockIdx.x * blockDim.x + threadIdx.x) >> 6;
  if (row >= nrows) return;
  const int slot = lane >> 4;
  const int ch = lane & 15;
  const int start = rowp[row];
  const int end = rowp[row + 1];
  const float dr = dis[row];

  float a0 = 0.f, a1 = 0.f, a2 = 0.f, a3 = 0.f, a4 = 0.f, a5 = 0.f, a6 = 0.f, a7 = 0.f;
  for (int j = start + slot; j < end; j += 8) {
    const int s1 = esrc[j];
    const int j2 = j + 4;
    const bool h2 = j2 < end;
    const int s2 = h2 ? esrc[j2] : s1;
    const float w1 = dis[s1];
    const float w2 = h2 ? dis[s2] : 0.f;
    const uint4 v1 = *(const uint4*)(xw + (size_t)s1 * 128 + ch * 8);
    const uint4 v2 = *(const uint4*)(xw + (size_t)s2 * 128 + ch * 8);
    a0 += w1 * __uint_as_float(v1.x << 16) + w2 * __uint_as_float(v2.x << 16);
    a1 += w1 * __uint_as_float(v1.x & 0xFFFF0000u) + w2 * __uint_as_float(v2.x & 0xFFFF0000u);
    a2 += w1 * __uint_as_float(v1.y << 16) + w2 * __uint_as_float(v2.y << 16);
    a3 += w1 * __uint_as_float(v1.y & 0xFFFF0000u) + w2 * __uint_as_float(v2.y & 0xFFFF0000u);
    a4 += w1 * __uint_as_float(v1.z << 16) + w2 * __uint_as_float(v2.z << 16);
    a5 += w1 * __uint_as_float(v1.z & 0xFFFF0000u) + w2 * __uint_as_float(v2.z & 0xFFFF0000u);
    a6 += w1 * __uint_as_float(v1.w << 16) + w2 * __uint_as_float(v2.w << 16);
    a7 += w1 * __uint_as_float(v1.w & 0xFFFF0000u) + w2 * __uint_as_float(v2.w & 0xFFFF0000u);
  }
  a0 += __shfl_xor(a0, 16, 64); a1 += __shfl_xor(a1, 16, 64);
  a2 += __shfl_xor(a2, 16, 64); a3 += __shfl_xor(a3, 16, 64);
  a4 += __shfl_xor(a4, 16, 64); a5 += __shfl_xor(a5, 16, 64);
  a6 += __shfl_xor(a6, 16, 64); a7 += __shfl_xor(a7, 16, 64);
  a0 += __shfl_xor(a0, 32, 64); a1 += __shfl_xor(a1, 32, 64);
  a2 += __shfl_xor(a2, 32, 64); a3 += __shfl_xor(a3, 32, 64);
  a4 += __shfl_xor(a4, 32, 64); a5 += __shfl_xor(a5, 32, 64);
  a6 += __shfl_xor(a6, 32, 64); a7 += __shfl_xor(a7, 32, 64);

  if (slot == 0) {
    const float4 b0 = *(const float4*)(bias + ch * 8);
    const float4 b1 = *(const float4*)(bias + ch * 8 + 4);
    float o0 = dr * a0 + b0.x, o1 = dr * a1 + b0.y;
    float o2 = dr * a2 + b0.z, o3 = dr * a3 + b0.w;
    float o4 = dr * a4 + b1.x, o5 = dr * a5 + b1.y;
    float o6 = dr * a6 + b1.z, o7 = dr * a7 + b1.w;
    o0 = o0 > 0.f ? o0 : SLOPE * o0; o1 = o1 > 0.f ? o1 : SLOPE * o1;
    o2 = o2 > 0.f ? o2 : SLOPE * o2; o3 = o3 > 0.f ? o3 : SLOPE * o3;
    o4 = o4 > 0.f ? o4 : SLOPE * o4; o5 = o5 > 0.f ? o5 : SLOPE * o5;
    o6 = o6 > 0.f ? o6 : SLOPE * o6; o7 = o7 > 0.f ? o7 : SLOPE * o7;
    uint4 o;
    o.x = pack2bf(o0, o1); o.y = pack2bf(o2, o3);
    o.z = pack2bf(o4, o5); o.w = pack2bf(o6, o7);
    *(uint4*)(out + (size_t)row * 128 + ch * 8) = o;
  }
}

// ---------------------------------------------------------------- batchnorm (paired)
__global__ __launch_bounds__(256) void bn_stats_pair_k(const ushort_t* __restrict__ XS,
                                                       const ushort_t* __restrict__ XR,
                                                       float* __restrict__ sums,
                                                       float* __restrict__ sumsq, int nrows) {
  __shared__ float ls[256], lq[256];
  const int br = blockIdx.y;
  const ushort_t* X = br ? XR : XS;
  const int t = threadIdx.x;
  const int c = t & 127;
  const int h = t >> 7;
  const int r0 = blockIdx.x * 256;
  const int r1 = min(r0 + 256, nrows);
  float s = 0.f, q = 0.f;
  for (int r = r0 + h; r < r1; r += 2) {
    float v = bf2f(X[(size_t)r * 128 + c]);
    s += v;
    q += v * v;
  }
  ls[t] = s;
  lq[t] = q;
  __syncthreads();
  if (t < 128) {
    s = ls[t] + ls[t + 128];
    q = lq[t] + lq[t + 128];
    atomicAdd(&sums[br * 128 + c], s);
    atomicAdd(&sumsq[br * 128 + c], q);
  }
}

__global__ __launch_bounds__(256) void bn_finalize_k(const float* __restrict__ sums,
                                                     const float* __restrict__ sumsq,
                                                     const float* __restrict__ gS,
                                                     const float* __restrict__ beS,
                                                     const float* __restrict__ gR,
                                                     const float* __restrict__ beR,
                                                     float* __restrict__ scl,
                                                     float* __restrict__ sht) {
  int t = threadIdx.x;  // 0..255
  int c = t & 127;
  int br = t >> 7;
  float mu = sums[t] * (1.f / (float)NN);
  float var = sumsq[t] * (1.f / (float)NN) - mu * mu;
  float gv = br ? gR[c] : gS[c];
  float bv = br ? beR[c] : beS[c];
  float s = gv * rsqrtf(var + FEPS);
  scl[t] = s;
  sht[t] = bv - mu * s;
}

// fold BN affine into both head weights (blockIdx.x: 0=cell, 1=drug)
struct FH {
  const float* W[2]; const float* b[2];
  ushort_t* Wf[2]; float* bf[2];
};
__global__ __launch_bounds__(128) void fold_head_k(FH fh, const float* __restrict__ scl,
                                                   const float* __restrict__ sht) {
  const int hI = blockIdx.x;
  const float* W = fh.W[hI];
  ushort_t* Wf = fh.Wf[hI];
  const int col = threadIdx.x;
  float acc = fh.b[hI][col];
  for (int k = 0; k < 256; k++) {
    const float w = W[(size_t)k * 128 + col];
    acc += sht[k] * w;
    Wf[(size_t)col * 256 + k] = f2bf(scl[k] * w);
  }
  fh.bf[hI][col] = acc;
}

// ---------------------------------------------------------------- launch
extern "C" void kernel_launch(void* const* d_in, const int* in_sizes, int n_in,
                              void* d_out, int out_size, void* d_ws, size_t ws_size,
                              hipStream_t stream) {
  const float* feature = (const float*)d_in[0];
  const int* sen_edge = (const int*)d_in[1];
  const int* res_edge = (const int*)d_in[2];
  const float* W_sen1 = (const float*)d_in[3];
  const float* b_sen1 = (const float*)d_in[4];
  const float* W_sen2 = (const float*)d_in[5];
  const float* b_sen2 = (const float*)d_in[6];
  const float* W_senfc = (const float*)d_in[7];
  const float* b_senfc = (const float*)d_in[8];
  const float* g_sen = (const float*)d_in[9];
  const float* be_sen = (const float*)d_in[10];
  const float* W_res1 = (const float*)d_in[11];
  const float* b_res1 = (const float*)d_in[12];
  const float* W_res2 = (const float*)d_in[13];
  const float* b_res2 = (const float*)d_in[14];
  const float* W_resfc = (const float*)d_in[15];
  const float* b_resfc = (const float*)d_in[16];
  const float* g_res = (const float*)d_in[17];
  const float* be_res = (const float*)d_in[18];
  const float* W_cell = (const float*)d_in[19];
  const float* b_cell = (const float*)d_in[20];
  const float* W_drug = (const float*)d_in[21];
  const float* b_drug = (const float*)d_in[22];
  float* out = (float*)d_out;

  const size_t NF = (size_t)NN * 128;
  char* wsb = (char*)d_ws;
  ushort_t* featb = (ushort_t*)wsb;                 // NF bf16 each
  ushort_t* xwb0 = featb + NF;                      // doubles as xall0
  ushort_t* xwb1 = xwb0 + NF;                       // doubles as xall1
  ushort_t* x1b0 = xwb1 + NF;
  ushort_t* x1b1 = x1b0 + NF;
  ushort_t* x2b0 = x1b1 + NF;
  ushort_t* x2b1 = x2b0 + NF;
  ushort_t* wt = x2b1 + NF;                         // weight pool
  ushort_t* W1tS = wt;                              // 128*128
  ushort_t* W2tS = W1tS + 128 * 128;
  ushort_t* WfctS = W2tS + 128 * 128;               // 128*384
  ushort_t* W1tR = WfctS + 128 * 384;
  ushort_t* W2tR = W1tR + 128 * 128;
  ushort_t* WfctR = W2tR + 128 * 128;
  ushort_t* Wcellf = WfctR + 128 * 384;             // 128*256 (folded)
  ushort_t* Wdrugf = Wcellf + 128 * 256;
  float* dis0 = (float*)(Wdrugf + 128 * 256);       // NN each
  float* dis1 = dis0 + NN;
  int* rowp0 = (int*)(dis1 + NN);                   // NN+1 each
  int* rowp1 = rowp0 + (NN + 1);
  int* esrc0 = rowp1 + (NN + 1);                    // EE each
  int* esrc1 = esrc0 + EE;
  uint_t* ebuf0 = (uint_t*)(esrc1 + EE);            // EE each
  uint_t* ebuf1 = ebuf0 + EE;
  int* tbl0 = (int*)(ebuf1 + EE);                   // NB*SNB each
  int* tbl1 = tbl0 + NB * SNB;
  int* off0 = tbl1 + NB * SNB;                      // NB*SNB each
  int* off1 = off0 + NB * SNB;
  int* total0 = off1 + NB * SNB;                    // NB each
  int* total1 = total0 + NB;
  int* bktoff0 = total1 + NB;                       // NB+1 each
  int* bktoff1 = bktoff0 + (NB + 1);
  float* sums = (float*)(bktoff1 + NB + 1);         // 2*128
  float* sumsq = sums + 256;                        // 2*128
  float* scl = sumsq + 256;                         // 2*128 (S,R)
  float* sht = scl + 256;                           // 2*128
  float* bcellf = sht + 256;
  float* bdrugf = bcellf + 128;

  const int MG = (NN + 127) / 128;          // 782
  const int GATH_N = (NN * 64 + 255) / 256; // 25000
  const int STAT_N = (NN + 255) / 256;      // 391

  feat_cvt_k<<<(int)(NF / 8 + 255) / 256, 256, 0, stream>>>(feature, featb, (int)(NF / 8));
  WCA wa;
  wa.w[0] = {W_sen1, W1tS, 128};  wa.w[1] = {W_sen2, W2tS, 128};
  wa.w[2] = {W_senfc, WfctS, 384}; wa.w[3] = {W_res1, W1tR, 128};
  wa.w[4] = {W_res2, W2tR, 128};  wa.w[5] = {W_resfc, WfctR, 384};
  wcvt_k<<<dim3(6, 24), 128, 0, stream>>>(wa);

  // CSR build: both branches per launch (blockIdx.y)
  CS cs = {};
  cs.src[0] = sen_edge; cs.src[1] = res_edge;
  cs.dst[0] = sen_edge + EE; cs.dst[1] = res_edge + EE;
  cs.tbl[0] = tbl0; cs.tbl[1] = tbl1;
  cs.off[0] = off0; cs.off[1] = off1;
  cs.total[0] = total0; cs.total[1] = total1;
  cs.bktoff[0] = bktoff0; cs.bktoff[1] = bktoff1;
  cs.rowp[0] = rowp0; cs.rowp[1] = rowp1;
  cs.dis[0] = dis0; cs.dis[1] = dis1;
  cs.esrc[0] = esrc0; cs.esrc[1] = esrc1;
  cs.ebuf[0] = ebuf0; cs.ebuf[1] = ebuf1;
  sort_count_k<<<dim3(SNB, 2), 256, 0, stream>>>(cs, EE);
  bkt_total_k<<<dim3(NB, 2), 256, 0, stream>>>(cs);
  bkt_scan_k<<<dim3(1, 2), 512, 0, stream>>>(cs, NN, EE);
  sort_offset_k<<<dim3(NB, 2), 256, 0, stream>>>(cs);
  sort_place_k<<<dim3(SNB, 2), 256, 0, stream>>>(cs, EE);
  bucket_fill2_k<<<dim3(NB, 2), 256, 0, stream>>>(cs, NN);

  // paired pipeline
  GP g1 = {};
  g1.X0[0] = featb; g1.X0[1] = featb;
  g1.Wt[0] = W1tS; g1.Wt[1] = W1tR;
  g1.Yb[0] = xwb0; g1.Yb[1] = xwb1;
  gemm_pair_k<<<dim3(MG, 2), 256, 0, stream>>>(g1, NN, 1, 0);

  GA ga = {};
  ga.rowp[0] = rowp0; ga.rowp[1] = rowp1;
  ga.esrc[0] = esrc0; ga.esrc[1] = esrc1;
  ga.dis[0] = dis0; ga.dis[1] = dis1;
  ga.xw[0] = xwb0; ga.xw[1] = xwb1;
  ga.bias[0] = b_sen1; ga.bias[1] = b_res1;
  ga.out[0] = x1b0; ga.out[1] = x1b1;
  gather_pair_k<<<dim3(GATH_N, 2), 256, 0, stream>>>(ga, NN);

  GP g2 = {};
  g2.X0[0] = x1b0; g2.X0[1] = x1b1;
  g2.Wt[0] = W2tS; g2.Wt[1] = W2tR;
  g2.Yb[0] = xwb0; g2.Yb[1] = xwb1;
  gemm_pair_k<<<dim3(MG, 2), 256, 0, stream>>>(g2, NN, 1, 0);

  ga.bias[0] = b_sen2; ga.bias[1] = b_res2;
  ga.out[0] = x2b0; ga.out[1] = x2b1;
  gather_pair_k<<<dim3(GATH_N, 2), 256, 0, stream>>>(ga, NN);

  // fc: writes xall into the (now dead) xwb buffers
  GP gf = {};
  gf.X0[0] = featb; gf.X0[1] = featb;
  gf.X1[0] = x1b0; gf.X1[1] = x1b1;
  gf.X2[0] = x2b0; gf.X2[1] = x2b1;
  gf.Wt[0] = WfctS; gf.Wt[1] = WfctR;
  gf.bias[0] = b_senfc; gf.bias[1] = b_resfc;
  gf.Yb[0] = xwb0; gf.Yb[1] = xwb1;
  gemm_pair_k<<<dim3(MG, 2), 256, 0, stream>>>(gf, NN, 3, 2);

  (void)hipMemsetAsync(sums, 0, 2 * 256 * sizeof(float), stream);
  bn_stats_pair_k<<<dim3(STAT_N, 2), 256, 0, stream>>>(xwb0, xwb1, sums, sumsq, NN);
  bn_finalize_k<<<1, 256, 0, stream>>>(sums, sumsq, g_sen, be_sen, g_res, be_res, scl, sht);

  FH fh = {};
  fh.W[0] = W_cell; fh.b[0] = b_cell; fh.Wf[0] = Wcellf; fh.bf[0] = bcellf;
  fh.W[1] = W_drug; fh.b[1] = b_drug; fh.Wf[1] = Wdrugf; fh.bf[1] = bdrugf;
  fold_head_k<<<2, 128, 0, stream>>>(fh, scl, sht);

  const int MGC = (NCELL + 127) / 128;
  const int MGD = (NDRUG + 127) / 128;
  GP gc = {};
  gc.X0[0] = xwb0; gc.X1[0] = xwb1;
  gc.Wt[0] = Wcellf; gc.bias[0] = bcellf; gc.Yf[0] = out;
  gemm_pair_k<<<dim3(MGC, 1), 256, 0, stream>>>(gc, NCELL, 2, 2);
  float* outD = out + (size_t)NCELL * 128;
  GP gd = {};
  gd.X0[0] = xwb0 + (size_t)NCELL * 128; gd.X1[0] = xwb1 + (size_t)NCELL * 128;
  gd.Wt[0] = Wdrugf; gd.bias[0] = bdrugf; gd.Yf[0] = outD;
  gemm_pair_k<<<dim3(MGD, 1), 256, 0, stream>>>(gd, NDRUG, 2, 2);
}

// Round 20
// 642.434 us; speedup vs baseline: 1.2923x; 1.0079x over previous
//
#include <hip/hip_runtime.h>

#define NN 100000
#define NCELL 40000
#define NDRUG 60000
#define EE 1600000
#define FEPS 1e-5f
#define SLOPE 0.2f
#define NB 391    // dst-buckets (256 rows each)
#define SCH 8192  // edges per sort block
#define SNB 196   // ceil(EE/SCH)

typedef unsigned short ushort_t;
typedef unsigned int uint_t;
typedef __attribute__((ext_vector_type(8))) __bf16 bf16x8;
typedef __attribute__((ext_vector_type(4))) float f32x4;

__device__ __forceinline__ ushort_t f2bf(float x) {
  uint_t u = __float_as_uint(x);
  u = (u + 0x7FFFu + ((u >> 16) & 1u)) >> 16;  // RNE
  return (ushort_t)u;
}
__device__ __forceinline__ uint_t pack2bf(float a, float b) {
  return (uint_t)f2bf(a) | ((uint_t)f2bf(b) << 16);
}
__device__ __forceinline__ float bf2f(ushort_t x) {
  return __uint_as_float(((uint_t)x) << 16);
}

// ---------------------------------------------------------------- converts
__global__ __launch_bounds__(256) void feat_cvt_k(const float* __restrict__ X,
                                                  ushort_t* __restrict__ Y, int n8) {
  int i = blockIdx.x * 256 + threadIdx.x;
  if (i >= n8) return;
  const float4* in4 = (const float4*)X;
  float4 a = in4[2 * i], b = in4[2 * i + 1];
  uint4 o;
  o.x = pack2bf(a.x, a.y); o.y = pack2bf(a.z, a.w);
  o.z = pack2bf(b.x, b.y); o.w = pack2bf(b.z, b.w);
  ((uint4*)Y)[i] = o;
}

struct WC { const float* s; ushort_t* d; int K; };
struct WCA { WC w[6]; };
__global__ __launch_bounds__(128) void wcvt_k(WCA a) {
  const WC wc = a.w[blockIdx.x];
  const int k0 = blockIdx.y * 16;
  if (k0 >= wc.K) return;
  const int col = threadIdx.x;
  const int k1 = min(k0 + 16, wc.K);
  for (int k = k0; k < k1; k++)
    wc.d[(size_t)col * wc.K + k] = f2bf(wc.s[(size_t)k * 128 + col]);
}

// ---- CSR build (branch-paired via blockIdx.y): zero global atomics ----
struct CS {
  const int* src[2]; const int* dst[2];
  int* tbl[2]; int* off[2]; int* total[2]; int* bktoff[2];
  int* rowp[2]; float* dis[2]; int* esrc[2]; uint_t* ebuf[2];
};

__global__ __launch_bounds__(256) void sort_count_k(CS cs, int E) {
  __shared__ int cnt[NB];
  const int br = blockIdx.y;
  const int* dst = cs.dst[br];
  int* tbl = cs.tbl[br];
  const int blk = blockIdx.x;
  for (int i = threadIdx.x; i < NB; i += 256) cnt[i] = 0;
  __syncthreads();
  const int e0 = blk * SCH, e1 = min(e0 + SCH, E);
  for (int e = e0 + threadIdx.x; e < e1; e += 256) atomicAdd(&cnt[dst[e] >> 8], 1);
  __syncthreads();
  for (int i = threadIdx.x; i < NB; i += 256) tbl[i * SNB + blk] = cnt[i];
}

__global__ __launch_bounds__(256) void bkt_total_k(CS cs) {
  __shared__ int sm[256];
  const int br = blockIdx.y;
  const int* tbl = cs.tbl[br];
  const int b = blockIdx.x;
  const int t = threadIdx.x;
  sm[t] = (t < SNB) ? tbl[b * SNB + t] : 0;
  __syncthreads();
  for (int off = 128; off > 0; off >>= 1) {
    if (t < off) sm[t] += sm[t + off];
    __syncthreads();
  }
  if (t == 0) cs.total[br][b] = sm[0];
}

__global__ __launch_bounds__(512) void bkt_scan_k(CS cs, int n, int E) {
  __shared__ int sm[512];
  const int br = blockIdx.y;
  const int* total = cs.total[br];
  int* bktoff = cs.bktoff[br];
  const int t = threadIdx.x;
  const int v = (t < NB) ? total[t] : 0;
  sm[t] = v;
  __syncthreads();
  for (int off = 1; off < 512; off <<= 1) {
    int u = (t >= off) ? sm[t - off] : 0;
    __syncthreads();
    sm[t] += u;
    __syncthreads();
  }
  if (t < NB) bktoff[t] = sm[t] - v;
  if (t == 0) { bktoff[NB] = E; cs.rowp[br][n] = E; }
}

__global__ __launch_bounds__(256) void sort_offset_k(CS cs) {
  __shared__ int sm[256];
  const int br = blockIdx.y;
  const int* tbl = cs.tbl[br];
  const int b = blockIdx.x;
  const int t = threadIdx.x;
  const int v = (t < SNB) ? tbl[b * SNB + t] : 0;
  sm[t] = v;
  __syncthreads();
  for (int o = 1; o < 256; o <<= 1) {
    int u = (t >= o) ? sm[t - o] : 0;
    __syncthreads();
    sm[t] += u;
    __syncthreads();
  }
  if (t < SNB) cs.off[br][b * SNB + t] = cs.bktoff[br][b] + sm[t] - v;
}

__global__ __launch_bounds__(256) void sort_place_k(CS cs, int E) {
  __shared__ int pos[NB];
  const int br = blockIdx.y;
  const int* src = cs.src[br];
  const int* dst = cs.dst[br];
  uint_t* ebuf = cs.ebuf[br];
  const int blk = blockIdx.x;
  for (int i = threadIdx.x; i < NB; i += 256) pos[i] = cs.off[br][i * SNB + blk];
  __syncthreads();
  const int e0 = blk * SCH, e1 = min(e0 + SCH, E);
  for (int e = e0 + threadIdx.x; e < e1; e += 256) {
    const int d = dst[e];
    const int p = atomicAdd(&pos[d >> 8], 1);
    ebuf[p] = (uint_t)src[e] | ((uint_t)(d & 255) << 17);
  }
}

__global__ __launch_bounds__(256) void bucket_fill2_k(CS cs, int n) {
  __shared__ int hist[256];
  __shared__ int scn[256];
  const int br = blockIdx.y;
  const uint_t* ebuf = cs.ebuf[br];
  const int* bktoff = cs.bktoff[br];
  const int b = blockIdx.x;
  const int t = threadIdx.x;
  const int r0 = b << 8;
  const int base = bktoff[b];
  const int end = bktoff[b + 1];
  hist[t] = 0;
  __syncthreads();
  for (int i = base + t; i < end; i += 256)
    atomicAdd(&hist[ebuf[i] >> 17], 1);
  __syncthreads();
  const int d = hist[t];
  scn[t] = d;
  __syncthreads();
  for (int off = 1; off < 256; off <<= 1) {
    int u = (t >= off) ? scn[t - off] : 0;
    __syncthreads();
    scn[t] += u;
    __syncthreads();
  }
  const int excl = scn[t] - d;
  const int r = r0 + t;
  if (r < n) {
    cs.rowp[br][r] = base + excl;
    cs.dis[br][r] = (d > 0) ? rsqrtf((float)d) : 0.f;
  }
  __syncthreads();
  hist[t] = excl;  // reuse as cursors
  __syncthreads();
  for (int i = base + t; i < end; i += 256) {
    const uint_t v = ebuf[i];
    const int rl = (int)(v >> 17);
    const int p = atomicAdd(&hist[rl], 1);
    cs.esrc[br][base + p] = (int)(v & 0x1FFFFu);
  }
}

// ---------------------------------------------------------------- MFMA GEMM (branch-paired)
// blockIdx.y selects pointer set; per-set row count nr[]; optional XCD-bijective
// blockIdx.x swizzle (m204) for L2 locality on the big N=100k GEMMs.
struct GP {
  const ushort_t* X0[2]; const ushort_t* X1[2]; const ushort_t* X2[2];
  const ushort_t* Wt[2]; const float* bias[2];
  float* Yf[2]; ushort_t* Yb[2];
  int nr[2];
};
#define SWZ(base, row, byte) ((char*)(base) + (((row)*256 + (byte)) ^ (((row)&7) << 4)))
#define FST 130
__global__ __launch_bounds__(256) void gemm_pair_k(GP gp, int nseg, int act, int doswz) {
  __shared__ ushort_t smem[128 * FST * 2];  // 66560B; stage uses first 64KB
  ushort_t* sA = smem;
  ushort_t* sB = smem + 128 * 128;
  const int br = blockIdx.y;
  const ushort_t* X0 = gp.X0[br];
  const ushort_t* X1 = gp.X1[br];
  const ushort_t* X2 = gp.X2[br];
  const ushort_t* Wt = gp.Wt[br];
  const float* bias = gp.bias[br];
  float* Yf = gp.Yf[br];
  ushort_t* Yb = gp.Yb[br];
  const int nrows = gp.nr[br];

  int bx = blockIdx.x;
  if (doswz) {  // bijective XCD swizzle (m204): contiguous chunk per XCD
    const int nwg = gridDim.x;
    const int q = nwg >> 3, r = nwg & 7;
    const int xcd = bx & 7, idx = bx >> 3;
    bx = (xcd < r ? xcd * (q + 1) : r * (q + 1) + (xcd - r) * q) + idx;
  }
  const int row0 = bx * 128;
  if (row0 >= nrows) return;  // uniform early-out (merged heads)

  const int t = threadIdx.x;
  const int wave = t >> 6;
  const int lane = t & 63;
  const int lane15 = lane & 15;
  const int lgrp = lane >> 4;  // 0..3
  const int Ktot = nseg * 128;

  const int tr = t >> 1;
  const int th = (t & 1) * 64;
  const int ra = min(row0 + tr, nrows - 1);
  const int wb = th * 2;

  f32x4 acc[2][8];
#pragma unroll
  for (int m = 0; m < 2; m++)
#pragma unroll
    for (int f = 0; f < 8; f++) acc[m][f] = (f32x4)0.f;

  for (int seg = 0; seg < nseg; seg++) {
    const ushort_t* Xp = (seg == 0) ? X0 : ((seg == 1) ? X1 : X2);
    const ushort_t* Ap = Xp + (size_t)ra * 128 + th;
    const ushort_t* Bp = Wt + (size_t)tr * Ktot + (seg << 7) + th;
    const uint4 a0 = *(const uint4*)(Ap + 0);
    const uint4 a1 = *(const uint4*)(Ap + 8);
    const uint4 a2 = *(const uint4*)(Ap + 16);
    const uint4 a3 = *(const uint4*)(Ap + 24);
    const uint4 a4 = *(const uint4*)(Ap + 32);
    const uint4 a5 = *(const uint4*)(Ap + 40);
    const uint4 a6 = *(const uint4*)(Ap + 48);
    const uint4 a7 = *(const uint4*)(Ap + 56);
    const uint4 b0 = *(const uint4*)(Bp + 0);
    const uint4 b1 = *(const uint4*)(Bp + 8);
    const uint4 b2 = *(const uint4*)(Bp + 16);
    const uint4 b3 = *(const uint4*)(Bp + 24);
    const uint4 b4 = *(const uint4*)(Bp + 32);
    const uint4 b5 = *(const uint4*)(Bp + 40);
    const uint4 b6 = *(const uint4*)(Bp + 48);
    const uint4 b7 = *(const uint4*)(Bp + 56);
    __syncthreads();
    *(uint4*)SWZ(sA, tr, wb + 0) = a0;
    *(uint4*)SWZ(sA, tr, wb + 16) = a1;
    *(uint4*)SWZ(sA, tr, wb + 32) = a2;
    *(uint4*)SWZ(sA, tr, wb + 48) = a3;
    *(uint4*)SWZ(sA, tr, wb + 64) = a4;
    *(uint4*)SWZ(sA, tr, wb + 80) = a5;
    *(uint4*)SWZ(sA, tr, wb + 96) = a6;
    *(uint4*)SWZ(sA, tr, wb + 112) = a7;
    *(uint4*)SWZ(sB, tr, wb + 0) = b0;
    *(uint4*)SWZ(sB, tr, wb + 16) = b1;
    *(uint4*)SWZ(sB, tr, wb + 32) = b2;
    *(uint4*)SWZ(sB, tr, wb + 48) = b3;
    *(uint4*)SWZ(sB, tr, wb + 64) = b4;
    *(uint4*)SWZ(sB, tr, wb + 80) = b5;
    *(uint4*)SWZ(sB, tr, wb + 96) = b6;
    *(uint4*)SWZ(sB, tr, wb + 112) = b7;
    __syncthreads();
#pragma unroll
    for (int kk = 0; kk < 4; kk++) {
      const int cb = kk * 64 + lgrp * 16;
      const int rA0 = wave * 32 + lane15;
      bf16x8 av0 = *(const bf16x8*)SWZ(sA, rA0, cb);
      bf16x8 av1 = *(const bf16x8*)SWZ(sA, rA0 + 16, cb);
#pragma unroll
      for (int f = 0; f < 8; f++) {
        bf16x8 wv = *(const bf16x8*)SWZ(sB, f * 16 + lane15, cb);
        acc[0][f] = __builtin_amdgcn_mfma_f32_16x16x32_bf16(av0, wv, acc[0][f], 0, 0, 0);
        acc[1][f] = __builtin_amdgcn_mfma_f32_16x16x32_bf16(av1, wv, acc[1][f], 0, 0, 0);
      }
    }
  }

  // ---- epilogue: bounce acc through LDS for coalesced stores ----
  __syncthreads();
  float* fb = (float*)smem;
  const int row0w = wave * 32;
#pragma unroll
  for (int m = 0; m < 2; m++)
#pragma unroll
    for (int f = 0; f < 8; f++)
#pragma unroll
      for (int j = 0; j < 4; j++)
        fb[(row0w + m * 16 + lgrp * 4 + j) * FST + f * 16 + lane15] = acc[m][f][j];
  __syncthreads();
  const int rowg = row0 + tr;
  if (rowg < nrows) {
    const float* rp = fb + tr * FST + th;
    if (Yf) {
      float* yp = Yf + (size_t)rowg * 128 + th;
#pragma unroll
      for (int q = 0; q < 16; q++) {
        float4 v = ((const float4*)rp)[q];
        if (bias) {
          const float4 bv = ((const float4*)(bias + th))[q];
          v.x += bv.x; v.y += bv.y; v.z += bv.z; v.w += bv.w;
        }
        if (act == 1) {
          v.x = v.x > 0.f ? v.x : SLOPE * v.x; v.y = v.y > 0.f ? v.y : SLOPE * v.y;
          v.z = v.z > 0.f ? v.z : SLOPE * v.z; v.w = v.w > 0.f ? v.w : SLOPE * v.w;
        } else if (act == 2) {
          v.x = v.x > 0.f ? v.x : 0.f; v.y = v.y > 0.f ? v.y : 0.f;
          v.z = v.z > 0.f ? v.z : 0.f; v.w = v.w > 0.f ? v.w : 0.f;
        }
        ((float4*)yp)[q] = v;
      }
    } else {
      ushort_t* yp = Yb + (size_t)rowg * 128 + th;
#pragma unroll
      for (int q = 0; q < 8; q++) {
        float4 v0 = ((const float4*)rp)[2 * q];
        float4 v1 = ((const float4*)rp)[2 * q + 1];
        if (bias) {
          const float4 c0 = ((const float4*)(bias + th))[2 * q];
          const float4 c1 = ((const float4*)(bias + th))[2 * q + 1];
          v0.x += c0.x; v0.y += c0.y; v0.z += c0.z; v0.w += c0.w;
          v1.x += c1.x; v1.y += c1.y; v1.z += c1.z; v1.w += c1.w;
        }
        if (act == 1) {
          v0.x = v0.x > 0.f ? v0.x : SLOPE * v0.x; v0.y = v0.y > 0.f ? v0.y : SLOPE * v0.y;
          v0.z = v0.z > 0.f ? v0.z : SLOPE * v0.z; v0.w = v0.w > 0.f ? v0.w : SLOPE * v0.w;
          v1.x = v1.x > 0.f ? v1.x : SLOPE * v1.x; v1.y = v1.y > 0.f ? v1.y : SLOPE * v1.y;
          v1.z = v1.z > 0.f ? v1.z : SLOPE * v1.z; v1.w = v1.w > 0.f ? v1.w : SLOPE * v1.w;
        } else if (act == 2) {
          v0.x = v0.x > 0.f ? v0.x : 0.f; v0.y = v0.y > 0.f ? v0.y : 0.f;
          v0.z = v0.z > 0.f ? v0.z : 0.f; v0.w = v0.w > 0.f ? v0.w : 0.f;
          v1.x = v1.x > 0.f ? v1.x : 0.f; v1.y = v1.y > 0.f ? v1.y : 0.f;
          v1.z = v1.z > 0.f ? v1.z : 0.f; v1.w = v1.w > 0.f ? v1.w : 0.f;
        }
        uint4 o;
        o.x = pack2bf(v0.x, v0.y); o.y = pack2bf(v0.z, v0.w);
        o.z = pack2bf(v1.x, v1.y); o.w = pack2bf(v1.z, v1.w);
        ((uint4*)yp)[q] = o;
      }
    }
  }
}

// ---------------------------------------------------------------- gather (branch-paired)
struct GA {
  const ushort_t* xw[2]; const int* rowp[2]; const int* esrc[2];
  const float* dis[2]; const float* bias[2]; ushort_t* out[2];
};
__global__ __launch_bounds__(256) void gather_pair_k(GA g, int nrows) {
  const int br = blockIdx.y;
  const ushort_t* xw = g.xw[br];
  const int* rowp = g.rowp[br];
  const int* esrc = g.esrc[br];
  const float* dis = g.dis[br];
  const float* bias = g.bias[br];
  ushort_t* out = g.out[br];

  const int lane = threadIdx.x & 63;
  const int row = (blockIdx.x * blockDim.x + threadIdx.x) >> 6;
  if (row >= nrows) return;
  const int slot = lane >> 4;
  const int ch = lane & 15;
  const int start = rowp[row];
  const int end = rowp[row + 1];
  const float dr = dis[row];

  float a0 = 0.f, a1 = 0.f, a2 = 0.f, a3 = 0.f, a4 = 0.f, a5 = 0.f, a6 = 0.f, a7 = 0.f;
  for (int j = start + slot; j < end; j += 8) {
    const int s1 = esrc[j];
    const int j2 = j + 4;
    const bool h2 = j2 < end;
    const int s2 = h2 ? esrc[j2] : s1;
    const float w1 = dis[s1];
    const float w2 = h2 ? dis[s2] : 0.f;
    const uint4 v1 = *(const uint4*)(xw + (size_t)s1 * 128 + ch * 8);
    const uint4 v2 = *(const uint4*)(xw + (size_t)s2 * 128 + ch * 8);
    a0 += w1 * __uint_as_float(v1.x << 16) + w2 * __uint_as_float(v2.x << 16);
    a1 += w1 * __uint_as_float(v1.x & 0xFFFF0000u) + w2 * __uint_as_float(v2.x & 0xFFFF0000u);
    a2 += w1 * __uint_as_float(v1.y << 16) + w2 * __uint_as_float(v2.y << 16);
    a3 += w1 * __uint_as_float(v1.y & 0xFFFF0000u) + w2 * __uint_as_float(v2.y & 0xFFFF0000u);
    a4 += w1 * __uint_as_float(v1.z << 16) + w2 * __uint_as_float(v2.z << 16);
    a5 += w1 * __uint_as_float(v1.z & 0xFFFF0000u) + w2 * __uint_as_float(v2.z & 0xFFFF0000u);
    a6 += w1 * __uint_as_float(v1.w << 16) + w2 * __uint_as_float(v2.w << 16);
    a7 += w1 * __uint_as_float(v1.w & 0xFFFF0000u) + w2 * __uint_as_float(v2.w & 0xFFFF0000u);
  }
  a0 += __shfl_xor(a0, 16, 64); a1 += __shfl_xor(a1, 16, 64);
  a2 += __shfl_xor(a2, 16, 64); a3 += __shfl_xor(a3, 16, 64);
  a4 += __shfl_xor(a4, 16, 64); a5 += __shfl_xor(a5, 16, 64);
  a6 += __shfl_xor(a6, 16, 64); a7 += __shfl_xor(a7, 16, 64);
  a0 += __shfl_xor(a0, 32, 64); a1 += __shfl_xor(a1, 32, 64);
  a2 += __shfl_xor(a2, 32, 64); a3 += __shfl_xor(a3, 32, 64);
  a4 += __shfl_xor(a4, 32, 64); a5 += __shfl_xor(a5, 32, 64);
  a6 += __shfl_xor(a6, 32, 64); a7 += __shfl_xor(a7, 32, 64);

  if (slot == 0) {
    const float4 b0 = *(const float4*)(bias + ch * 8);
    const float4 b1 = *(const float4*)(bias + ch * 8 + 4);
    float o0 = dr * a0 + b0.x, o1 = dr * a1 + b0.y;
    float o2 = dr * a2 + b0.z, o3 = dr * a3 + b0.w;
    float o4 = dr * a4 + b1.x, o5 = dr * a5 + b1.y;
    float o6 = dr * a6 + b1.z, o7 = dr * a7 + b1.w;
    o0 = o0 > 0.f ? o0 : SLOPE * o0; o1 = o1 > 0.f ? o1 : SLOPE * o1;
    o2 = o2 > 0.f ? o2 : SLOPE * o2; o3 = o3 > 0.f ? o3 : SLOPE * o3;
    o4 = o4 > 0.f ? o4 : SLOPE * o4; o5 = o5 > 0.f ? o5 : SLOPE * o5;
    o6 = o6 > 0.f ? o6 : SLOPE * o6; o7 = o7 > 0.f ? o7 : SLOPE * o7;
    uint4 o;
    o.x = pack2bf(o0, o1); o.y = pack2bf(o2, o3);
    o.z = pack2bf(o4, o5); o.w = pack2bf(o6, o7);
    *(uint4*)(out + (size_t)row * 128 + ch * 8) = o;
  }
}

// ---------------------------------------------------------------- batchnorm (paired)
__global__ __launch_bounds__(256) void bn_stats_pair_k(const ushort_t* __restrict__ XS,
                                                       const ushort_t* __restrict__ XR,
                                                       float* __restrict__ sums,
                                                       float* __restrict__ sumsq, int nrows) {
  __shared__ float ls[256], lq[256];
  const int br = blockIdx.y;
  const ushort_t* X = br ? XR : XS;
  const int t = threadIdx.x;
  const int c = t & 127;
  const int h = t >> 7;
  const int r0 = blockIdx.x * 256;
  const int r1 = min(r0 + 256, nrows);
  float s = 0.f, q = 0.f;
  for (int r = r0 + h; r < r1; r += 2) {
    float v = bf2f(X[(size_t)r * 128 + c]);
    s += v;
    q += v * v;
  }
  ls[t] = s;
  lq[t] = q;
  __syncthreads();
  if (t < 128) {
    s = ls[t] + ls[t + 128];
    q = lq[t] + lq[t + 128];
    atomicAdd(&sums[br * 128 + c], s);
    atomicAdd(&sumsq[br * 128 + c], q);
  }
}

// fold BN affine into both head weights (blockIdx.x: 0=cell, 1=drug).
// Each block recomputes scl/sht (trivial) from sums/sumsq -> no separate finalize.
struct FH {
  const float* W[2]; const float* b[2];
  ushort_t* Wf[2]; float* bf[2];
  const float* gS; const float* beS; const float* gR; const float* beR;
};
__global__ __launch_bounds__(128) void fold_head_k(FH fh, const float* __restrict__ sums,
                                                   const float* __restrict__ sumsq) {
  __shared__ float lscl[256], lsht[256];
  const int col = threadIdx.x;
  for (int k2 = col; k2 < 256; k2 += 128) {
    const int c = k2 & 127;
    const int br = k2 >> 7;
    const float mu = sums[k2] * (1.f / (float)NN);
    const float var = sumsq[k2] * (1.f / (float)NN) - mu * mu;
    const float gv = br ? fh.gR[c] : fh.gS[c];
    const float bv = br ? fh.beR[c] : fh.beS[c];
    const float s = gv * rsqrtf(var + FEPS);
    lscl[k2] = s;
    lsht[k2] = bv - mu * s;
  }
  __syncthreads();
  const int hI = blockIdx.x;
  const float* W = fh.W[hI];
  ushort_t* Wf = fh.Wf[hI];
  float acc = fh.b[hI][col];
  for (int k = 0; k < 256; k++) {
    const float w = W[(size_t)k * 128 + col];
    acc += lsht[k] * w;
    Wf[(size_t)col * 256 + k] = f2bf(lscl[k] * w);
  }
  fh.bf[hI][col] = acc;
}

// ---------------------------------------------------------------- launch
extern "C" void kernel_launch(void* const* d_in, const int* in_sizes, int n_in,
                              void* d_out, int out_size, void* d_ws, size_t ws_size,
                              hipStream_t stream) {
  const float* feature = (const float*)d_in[0];
  const int* sen_edge = (const int*)d_in[1];
  const int* res_edge = (const int*)d_in[2];
  const float* W_sen1 = (const float*)d_in[3];
  const float* b_sen1 = (const float*)d_in[4];
  const float* W_sen2 = (const float*)d_in[5];
  const float* b_sen2 = (const float*)d_in[6];
  const float* W_senfc = (const float*)d_in[7];
  const float* b_senfc = (const float*)d_in[8];
  const float* g_sen = (const float*)d_in[9];
  const float* be_sen = (const float*)d_in[10];
  const float* W_res1 = (const float*)d_in[11];
  const float* b_res1 = (const float*)d_in[12];
  const float* W_res2 = (const float*)d_in[13];
  const float* b_res2 = (const float*)d_in[14];
  const float* W_resfc = (const float*)d_in[15];
  const float* b_resfc = (const float*)d_in[16];
  const float* g_res = (const float*)d_in[17];
  const float* be_res = (const float*)d_in[18];
  const float* W_cell = (const float*)d_in[19];
  const float* b_cell = (const float*)d_in[20];
  const float* W_drug = (const float*)d_in[21];
  const float* b_drug = (const float*)d_in[22];
  float* out = (float*)d_out;

  const size_t NF = (size_t)NN * 128;
  char* wsb = (char*)d_ws;
  ushort_t* featb = (ushort_t*)wsb;                 // NF bf16 each
  ushort_t* xwb0 = featb + NF;                      // doubles as xall0
  ushort_t* xwb1 = xwb0 + NF;                       // doubles as xall1
  ushort_t* x1b0 = xwb1 + NF;
  ushort_t* x1b1 = x1b0 + NF;
  ushort_t* x2b0 = x1b1 + NF;
  ushort_t* x2b1 = x2b0 + NF;
  ushort_t* wt = x2b1 + NF;                         // weight pool
  ushort_t* W1tS = wt;                              // 128*128
  ushort_t* W2tS = W1tS + 128 * 128;
  ushort_t* WfctS = W2tS + 128 * 128;               // 128*384
  ushort_t* W1tR = WfctS + 128 * 384;
  ushort_t* W2tR = W1tR + 128 * 128;
  ushort_t* WfctR = W2tR + 128 * 128;
  ushort_t* Wcellf = WfctR + 128 * 384;             // 128*256 (folded)
  ushort_t* Wdrugf = Wcellf + 128 * 256;
  float* dis0 = (float*)(Wdrugf + 128 * 256);       // NN each
  float* dis1 = dis0 + NN;
  int* rowp0 = (int*)(dis1 + NN);                   // NN+1 each
  int* rowp1 = rowp0 + (NN + 1);
  int* esrc0 = rowp1 + (NN + 1);                    // EE each
  int* esrc1 = esrc0 + EE;
  uint_t* ebuf0 = (uint_t*)(esrc1 + EE);            // EE each
  uint_t* ebuf1 = ebuf0 + EE;
  int* tbl0 = (int*)(ebuf1 + EE);                   // NB*SNB each
  int* tbl1 = tbl0 + NB * SNB;
  int* off0 = tbl1 + NB * SNB;                      // NB*SNB each
  int* off1 = off0 + NB * SNB;
  int* total0 = off1 + NB * SNB;                    // NB each
  int* total1 = total0 + NB;
  int* bktoff0 = total1 + NB;                       // NB+1 each
  int* bktoff1 = bktoff0 + (NB + 1);
  float* sums = (float*)(bktoff1 + NB + 1);         // 2*128
  float* sumsq = sums + 256;                        // 2*128
  float* bcellf = sumsq + 256;                      // 128 each
  float* bdrugf = bcellf + 128;

  const int MG = (NN + 127) / 128;          // 782
  const int GATH_N = (NN * 64 + 255) / 256; // 25000
  const int STAT_N = (NN + 255) / 256;      // 391

  feat_cvt_k<<<(int)(NF / 8 + 255) / 256, 256, 0, stream>>>(feature, featb, (int)(NF / 8));
  WCA wa;
  wa.w[0] = {W_sen1, W1tS, 128};  wa.w[1] = {W_sen2, W2tS, 128};
  wa.w[2] = {W_senfc, WfctS, 384}; wa.w[3] = {W_res1, W1tR, 128};
  wa.w[4] = {W_res2, W2tR, 128};  wa.w[5] = {W_resfc, WfctR, 384};
  wcvt_k<<<dim3(6, 24), 128, 0, stream>>>(wa);

  // CSR build: both branches per launch (blockIdx.y)
  CS cs = {};
  cs.src[0] = sen_edge; cs.src[1] = res_edge;
  cs.dst[0] = sen_edge + EE; cs.dst[1] = res_edge + EE;
  cs.tbl[0] = tbl0; cs.tbl[1] = tbl1;
  cs.off[0] = off0; cs.off[1] = off1;
  cs.total[0] = total0; cs.total[1] = total1;
  cs.bktoff[0] = bktoff0; cs.bktoff[1] = bktoff1;
  cs.rowp[0] = rowp0; cs.rowp[1] = rowp1;
  cs.dis[0] = dis0; cs.dis[1] = dis1;
  cs.esrc[0] = esrc0; cs.esrc[1] = esrc1;
  cs.ebuf[0] = ebuf0; cs.ebuf[1] = ebuf1;
  sort_count_k<<<dim3(SNB, 2), 256, 0, stream>>>(cs, EE);
  bkt_total_k<<<dim3(NB, 2), 256, 0, stream>>>(cs);
  bkt_scan_k<<<dim3(1, 2), 512, 0, stream>>>(cs, NN, EE);
  sort_offset_k<<<dim3(NB, 2), 256, 0, stream>>>(cs);
  sort_place_k<<<dim3(SNB, 2), 256, 0, stream>>>(cs, EE);
  bucket_fill2_k<<<dim3(NB, 2), 256, 0, stream>>>(cs, NN);

  // paired pipeline
  GP g1 = {};
  g1.X0[0] = featb; g1.X0[1] = featb;
  g1.Wt[0] = W1tS; g1.Wt[1] = W1tR;
  g1.Yb[0] = xwb0; g1.Yb[1] = xwb1;
  g1.nr[0] = NN; g1.nr[1] = NN;
  gemm_pair_k<<<dim3(MG, 2), 256, 0, stream>>>(g1, 1, 0, 1);

  GA ga = {};
  ga.rowp[0] = rowp0; ga.rowp[1] = rowp1;
  ga.esrc[0] = esrc0; ga.esrc[1] = esrc1;
  ga.dis[0] = dis0; ga.dis[1] = dis1;
  ga.xw[0] = xwb0; ga.xw[1] = xwb1;
  ga.bias[0] = b_sen1; ga.bias[1] = b_res1;
  ga.out[0] = x1b0; ga.out[1] = x1b1;
  gather_pair_k<<<dim3(GATH_N, 2), 256, 0, stream>>>(ga, NN);

  GP g2 = {};
  g2.X0[0] = x1b0; g2.X0[1] = x1b1;
  g2.Wt[0] = W2tS; g2.Wt[1] = W2tR;
  g2.Yb[0] = xwb0; g2.Yb[1] = xwb1;
  g2.nr[0] = NN; g2.nr[1] = NN;
  gemm_pair_k<<<dim3(MG, 2), 256, 0, stream>>>(g2, 1, 0, 1);

  ga.bias[0] = b_sen2; ga.bias[1] = b_res2;
  ga.out[0] = x2b0; ga.out[1] = x2b1;
  gather_pair_k<<<dim3(GATH_N, 2), 256, 0, stream>>>(ga, NN);

  // fc: writes xall into the (now dead) xwb buffers
  GP gf = {};
  gf.X0[0] = featb; gf.X0[1] = featb;
  gf.X1[0] = x1b0; gf.X1[1] = x1b1;
  gf.X2[0] = x2b0; gf.X2[1] = x2b1;
  gf.Wt[0] = WfctS; gf.Wt[1] = WfctR;
  gf.bias[0] = b_senfc; gf.bias[1] = b_resfc;
  gf.Yb[0] = xwb0; gf.Yb[1] = xwb1;
  gf.nr[0] = NN; gf.nr[1] = NN;
  gemm_pair_k<<<dim3(MG, 2), 256, 0, stream>>>(gf, 3, 2, 1);

  (void)hipMemsetAsync(sums, 0, 2 * 256 * sizeof(float), stream);
  bn_stats_pair_k<<<dim3(STAT_N, 2), 256, 0, stream>>>(xwb0, xwb1, sums, sumsq, NN);

  FH fh = {};
  fh.W[0] = W_cell; fh.b[0] = b_cell; fh.Wf[0] = Wcellf; fh.bf[0] = bcellf;
  fh.W[1] = W_drug; fh.b[1] = b_drug; fh.Wf[1] = Wdrugf; fh.bf[1] = bdrugf;
  fh.gS = g_sen; fh.beS = be_sen; fh.gR = g_res; fh.beR = be_res;
  fold_head_k<<<2, 128, 0, stream>>>(fh, sums, sumsq);

  // merged heads: one dispatch, blockIdx.y = head (0=cell, 1=drug)
  const int MGD = (NDRUG + 127) / 128;  // 469 >= MGC
  float* outD = out + (size_t)NCELL * 128;
  GP gh = {};
  gh.X0[0] = xwb0; gh.X1[0] = xwb1;
  gh.Wt[0] = Wcellf; gh.bias[0] = bcellf; gh.Yf[0] = out;
  gh.nr[0] = NCELL;
  gh.X0[1] = xwb0 + (size_t)NCELL * 128; gh.X1[1] = xwb1 + (size_t)NCELL * 128;
  gh.Wt[1] = Wdrugf; gh.bias[1] = bdrugf; gh.Yf[1] = outD;
  gh.nr[1] = NDRUG;
  gemm_pair_k<<<dim3(MGD, 2), 256, 0, stream>>>(gh, 2, 2, 0);
}